// Round 1
// baseline (373.247 us; speedup 1.0000x reference)
//
#include <hip/hip_runtime.h>
#include <hip/hip_bf16.h>
#include <cstdint>
#include <cmath>

// ---------------------------------------------------------------------------
// Hamilton_V5: H-net gradient (analytic VJP) + A-net with fused einsum epilogue.
// All GEMMs: bf16 MFMA 16x16x32, fp32 accum, m97-style 128x128x32 tiles.
// ---------------------------------------------------------------------------

typedef __bf16 bf16_t;
typedef __bf16 bf16x4_t __attribute__((ext_vector_type(4)));
typedef __bf16 bf16x8_t __attribute__((ext_vector_type(8)));
typedef float f32x4_t __attribute__((ext_vector_type(4)));

#define DIMD 128
#define NROW 4096

// async global->LDS, 16B per lane; LDS dest = wave-uniform base + lane*16
__device__ __forceinline__ void g2l16(const void* gp, void* lp) {
  __builtin_amdgcn_global_load_lds(
      reinterpret_cast<__attribute__((address_space(1))) void*>(
          reinterpret_cast<uintptr_t>(gp)),
      reinterpret_cast<__attribute__((address_space(3))) void*>(
          reinterpret_cast<uintptr_t>(lp)),
      16, 0, 0);
}

// ---------------------------------------------------------------------------
// Generic bf16 GEMM, C = A(MxK) * B^T(NxK)^T, tiles BM=BN=128, BK=32,
// 256 threads = 4 waves in 2x2, each wave 64x64 (4x4 MFMA 16x16x32 subtiles).
// EPI 0: out(bf16) = tanh(C + bias[n]), row-major ldo
// EPI 1: out(f32)  = (n0<128 ? +C : -C)  -> d_out (dx | dv_H)
// EPI 2: fused A3: per row m, out[m,128+blockIdx.y] += sum_n tanh(C+Ab3)*u[n]
// ---------------------------------------------------------------------------
template <int EPI>
__global__ __launch_bounds__(256) void gemm_bt(
    const bf16_t* __restrict__ A, int lda, const bf16_t* __restrict__ B,
    int ldb, int K, const float* __restrict__ bias, void* __restrict__ outp,
    int ldo, const float* __restrict__ ab3, const float* __restrict__ uvec) {
  constexpr int BM = 128, BN = 128, BK = 32;
  __shared__ __align__(16) bf16_t As[BM * BK];
  __shared__ __align__(16) bf16_t Bs[BN * BK];

  const int m0 = blockIdx.x * BM;
  const int n0 = blockIdx.y * BN;
  const int tid = threadIdx.x;
  const int wave = tid >> 6;
  const int lane = tid & 63;
  const int wm = wave >> 1;  // 2x2 wave grid
  const int wn = wave & 1;

  const int sr = lane >> 2;        // staging row within a 16-row chunk
  const int sk = (lane & 3) * 8;   // staging k offset (elements, 16B)
  const int fr = lane & 15;        // fragment m/n index
  const int fk = (lane >> 4) * 8;  // fragment k offset

  f32x4_t acc[4][4] = {};

  for (int k0 = 0; k0 < K; k0 += BK) {
    if (k0) __syncthreads();
#pragma unroll
    for (int t = 0; t < 2; ++t) {
      const int rb = wave * 32 + t * 16;
      g2l16(A + (size_t)(m0 + rb + sr) * lda + (k0 + sk), As + rb * BK);
      g2l16(B + (size_t)(n0 + rb + sr) * ldb + (k0 + sk), Bs + rb * BK);
    }
    __syncthreads();  // drains vmcnt -> tiles visible

    bf16x8_t af[4], bb[4];
#pragma unroll
    for (int t = 0; t < 4; ++t) {
      af[t] = *(const bf16x8_t*)(As + (wm * 64 + t * 16 + fr) * BK + fk);
      bb[t] = *(const bf16x8_t*)(Bs + (wn * 64 + t * 16 + fr) * BK + fk);
    }
#pragma unroll
    for (int i = 0; i < 4; ++i)
#pragma unroll
      for (int j = 0; j < 4; ++j)
        acc[i][j] =
            __builtin_amdgcn_mfma_f32_16x16x32_bf16(af[i], bb[j], acc[i][j], 0, 0, 0);
  }

  // C/D layout (m89-verified): col = lane&15, row = (lane>>4)*4 + reg
  if constexpr (EPI == 0) {
    bf16_t* O = (bf16_t*)outp;
#pragma unroll
    for (int i = 0; i < 4; ++i) {
      const int row = m0 + wm * 64 + i * 16 + (lane >> 4) * 4;
#pragma unroll
      for (int j = 0; j < 4; ++j) {
        const int col = n0 + wn * 64 + j * 16 + fr;
        const float b = bias[col];
#pragma unroll
        for (int r = 0; r < 4; ++r)
          O[(size_t)(row + r) * ldo + col] = (bf16_t)tanhf(acc[i][j][r] + b);
      }
    }
  } else if constexpr (EPI == 1) {
    float* O = (float*)outp;
    const float sgn = (n0 >= DIMD) ? -1.f : 1.f;  // dv = -g[:, d:]
#pragma unroll
    for (int i = 0; i < 4; ++i) {
      const int row = m0 + wm * 64 + i * 16 + (lane >> 4) * 4;
#pragma unroll
      for (int j = 0; j < 4; ++j) {
        const int col = n0 + wn * 64 + j * 16 + fr;
#pragma unroll
        for (int r = 0; r < 4; ++r)
          O[(size_t)(row + r) * ldo + col] = sgn * acc[i][j][r];
      }
    }
  } else {
    // fused: out[m, 128+i0] += sum_{j=0..127} tanh(C[m,j] + Ab3[i0*128+j])*u[j]
    __shared__ float red[128];
    __shared__ float us[128];
    __shared__ float a3s[128];
    if (tid < 128) {
      red[tid] = 0.f;
      us[tid] = uvec[tid];
      a3s[tid] = ab3[n0 + tid];
    }
    __syncthreads();
#pragma unroll
    for (int i = 0; i < 4; ++i) {
      float sums[4] = {0.f, 0.f, 0.f, 0.f};
#pragma unroll
      for (int j = 0; j < 4; ++j) {
        const int c = wn * 64 + j * 16 + fr;
        const float uu = us[c];
        const float b3 = a3s[c];
#pragma unroll
        for (int r = 0; r < 4; ++r) sums[r] += tanhf(acc[i][j][r] + b3) * uu;
      }
#pragma unroll
      for (int d = 1; d < 16; d <<= 1)
#pragma unroll
        for (int r = 0; r < 4; ++r) sums[r] += __shfl_xor(sums[r], d, 64);
      if (fr == 0) {
        const int rowb = wm * 64 + i * 16 + (lane >> 4) * 4;
#pragma unroll
        for (int r = 0; r < 4; ++r) atomicAdd(&red[rowb + r], sums[r]);
      }
    }
    __syncthreads();
    if (tid < 128) {
      float* O = (float*)outp;
      const size_t idx = (size_t)(m0 + tid) * (2 * DIMD) + DIMD + blockIdx.y;
      O[idx] += red[tid];  // dv_H written earlier by EPI==1 kernel
    }
  }
}

// ---------------------------------------------------------------------------
// fp32 -> bf16 straight conversion (layout preserved)
// ---------------------------------------------------------------------------
__global__ __launch_bounds__(256) void cvt_bf16(const float4* __restrict__ in,
                                                bf16x4_t* __restrict__ out,
                                                int n4) {
  const int i = blockIdx.x * 256 + threadIdx.x;
  if (i >= n4) return;
  const float4 v = in[i];
  bf16x4_t o = {(bf16_t)v.x, (bf16_t)v.y, (bf16_t)v.z, (bf16_t)v.w};
  out[i] = o;
}

// fp32 RxC -> bf16 CxR transpose (all dims multiples of 32)
__global__ __launch_bounds__(256) void tcvt(const float* __restrict__ in,
                                            bf16_t* __restrict__ out, int R,
                                            int C) {
  __shared__ float t[32][33];
  const int c0 = blockIdx.x * 32;
  const int r0 = blockIdx.y * 32;
  const int tx = threadIdx.x & 31;
  const int ty = threadIdx.x >> 5;  // 0..7
#pragma unroll
  for (int k = 0; k < 4; ++k)
    t[ty + k * 8][tx] = in[(size_t)(r0 + ty + k * 8) * C + c0 + tx];
  __syncthreads();
#pragma unroll
  for (int k = 0; k < 4; ++k)
    out[(size_t)(c0 + ty + k * 8) * R + r0 + tx] = (bf16_t)t[tx][ty + k * 8];
}

// ---------------------------------------------------------------------------
// per-row: pre2 = h.Hw2, y = tanh(pre2+Hb2), s = 1-y^2,
//          w_j = s * Hw2_j * (1 - h_j^2)    (one wave per row)
// ---------------------------------------------------------------------------
__global__ __launch_bounds__(64) void hgrad_w(const bf16_t* __restrict__ h,
                                              const float* __restrict__ Hw2,
                                              const float* __restrict__ Hb2,
                                              bf16_t* __restrict__ w) {
  const int row = blockIdx.x;
  const int lane = threadIdx.x;
  float hv[10], wv[10];
  float pre2 = 0.f;
#pragma unroll
  for (int t = 0; t < 10; ++t) {
    const int j = lane + t * 64;
    hv[t] = (float)h[(size_t)row * 640 + j];
    wv[t] = Hw2[j];
    pre2 += hv[t] * wv[t];
  }
#pragma unroll
  for (int d = 1; d < 64; d <<= 1) pre2 += __shfl_xor(pre2, d, 64);
  const float y = tanhf(pre2 + Hb2[0]);
  const float s = 1.f - y * y;
#pragma unroll
  for (int t = 0; t < 10; ++t) {
    const int j = lane + t * 64;
    w[(size_t)row * 640 + j] = (bf16_t)(s * wv[t] * (1.f - hv[t] * hv[t]));
  }
}

// ---------------------------------------------------------------------------
extern "C" void kernel_launch(void* const* d_in, const int* in_sizes, int n_in,
                              void* d_out, int out_size, void* d_ws,
                              size_t ws_size, hipStream_t stream) {
  (void)in_sizes;
  (void)n_in;
  (void)out_size;
  (void)ws_size;
  // setup_inputs order: t, inp, Hw1, Hb1, Hw2, Hb2, Aw1, Ab1, Aw2, Ab2, Aw3, Ab3, u
  const float* inp = (const float*)d_in[1];
  const float* Hw1 = (const float*)d_in[2];
  const float* Hb1 = (const float*)d_in[3];
  const float* Hw2 = (const float*)d_in[4];
  const float* Hb2 = (const float*)d_in[5];
  const float* Aw1 = (const float*)d_in[6];
  const float* Ab1 = (const float*)d_in[7];
  const float* Aw2 = (const float*)d_in[8];
  const float* Ab2 = (const float*)d_in[9];
  const float* Aw3 = (const float*)d_in[10];
  const float* Ab3 = (const float*)d_in[11];
  const float* u = (const float*)d_in[12];
  float* out = (float*)d_out;

  // workspace layout (~60.5 MB total)
  char* ws = (char*)d_ws;
  bf16_t* inp_bf = (bf16_t*)ws;  ws += (size_t)NROW * 256 * 2;       // 2 MB
  bf16_t* Hw1_bf = (bf16_t*)ws;  ws += (size_t)256 * 640 * 2;        // B^T for H-bwd
  bf16_t* Hw1T = (bf16_t*)ws;    ws += (size_t)640 * 256 * 2;        // B^T for H-fwd
  bf16_t* Aw1T = (bf16_t*)ws;    ws += (size_t)512 * 128 * 2;
  bf16_t* Aw2T = (bf16_t*)ws;    ws += (size_t)1024 * 512 * 2;
  bf16_t* Aw3T = (bf16_t*)ws;    ws += (size_t)16384 * 1024 * 2;     // 32 MB
  bf16_t* h_bf = (bf16_t*)ws;    ws += (size_t)NROW * 640 * 2;
  bf16_t* w_bf = (bf16_t*)ws;    ws += (size_t)NROW * 640 * 2;
  bf16_t* h1_bf = (bf16_t*)ws;   ws += (size_t)NROW * 512 * 2;
  bf16_t* h2_bf = (bf16_t*)ws;   ws += (size_t)NROW * 1024 * 2;

  // ---- conversions (rerun every call: inputs restored each timed launch) ----
  cvt_bf16<<<(NROW * 256 / 4 + 255) / 256, 256, 0, stream>>>(
      (const float4*)inp, (bf16x4_t*)inp_bf, NROW * 256 / 4);
  cvt_bf16<<<(256 * 640 / 4 + 255) / 256, 256, 0, stream>>>(
      (const float4*)Hw1, (bf16x4_t*)Hw1_bf, 256 * 640 / 4);
  tcvt<<<dim3(640 / 32, 256 / 32), 256, 0, stream>>>(Hw1, Hw1T, 256, 640);
  tcvt<<<dim3(512 / 32, 128 / 32), 256, 0, stream>>>(Aw1, Aw1T, 128, 512);
  tcvt<<<dim3(1024 / 32, 512 / 32), 256, 0, stream>>>(Aw2, Aw2T, 512, 1024);
  tcvt<<<dim3(16384 / 32, 1024 / 32), 256, 0, stream>>>(Aw3, Aw3T, 1024, 16384);

  // ---- H net: h = tanh(inp @ Hw1 + Hb1)  (M=4096, K=256, N=640) ----
  gemm_bt<0><<<dim3(32, 5), 256, 0, stream>>>(inp_bf, 256, Hw1T, 256, 256, Hb1,
                                              h_bf, 640, nullptr, nullptr);
  // w_j = s * Hw2_j * (1 - h_j^2)
  hgrad_w<<<NROW, 64, 0, stream>>>(h_bf, Hw2, Hb2, w_bf);
  // g = w @ Hw1^T -> out = [g[:, :128] | -g[:, 128:]]  (M=4096, K=640, N=256)
  gemm_bt<1><<<dim3(32, 2), 256, 0, stream>>>(w_bf, 640, Hw1_bf, 640, 640,
                                              nullptr, out, 256, nullptr, nullptr);

  // ---- A net ----
  // h1 = tanh(x @ Aw1 + Ab1), x = inp[:, :128]  (K=128, N=512)
  gemm_bt<0><<<dim3(32, 4), 256, 0, stream>>>(inp_bf, 256, Aw1T, 128, 128, Ab1,
                                              h1_bf, 512, nullptr, nullptr);
  // h2 = tanh(h1 @ Aw2 + Ab2)  (K=512, N=1024)
  gemm_bt<0><<<dim3(32, 8), 256, 0, stream>>>(h1_bf, 512, Aw2T, 512, 512, Ab2,
                                              h2_bf, 1024, nullptr, nullptr);
  // fused A3: out[:, 128+i0] += sum_j tanh(h2@Aw3 + Ab3)[., i0*128+j] * u[j]
  gemm_bt<2><<<dim3(32, 128), 256, 0, stream>>>(h2_bf, 1024, Aw3T, 1024, 1024,
                                                nullptr, out, 256, Ab3, u);
}

// Round 2
// 335.617 us; speedup vs baseline: 1.1121x; 1.1121x over previous
//
#include <hip/hip_runtime.h>
#include <hip/hip_bf16.h>
#include <cstdint>
#include <cmath>

// ---------------------------------------------------------------------------
// Hamilton_V5: H-net gradient (analytic VJP) + A-net with fused einsum epilogue.
// All GEMMs: bf16 MFMA 16x16x32, fp32 accum, m97-style 128x128x32 tiles.
// R2: LDS xor-swizzle (kills 8-way ds_read_b128 bank conflicts), fast tanh,
//     merged prep kernels.
// ---------------------------------------------------------------------------

typedef __bf16 bf16_t;
typedef __bf16 bf16x4_t __attribute__((ext_vector_type(4)));
typedef __bf16 bf16x8_t __attribute__((ext_vector_type(8)));
typedef float f32x4_t __attribute__((ext_vector_type(4)));

#define DIMD 128
#define NROW 4096

// branchless tanh: t=2^(2x*log2e); tanh=1-2/(t+1). Saturates correctly at +-inf.
__device__ __forceinline__ float fast_tanh(float x) {
  float t = __builtin_amdgcn_exp2f(x * 2.8853900817779268f);
  return 1.f - 2.f * __builtin_amdgcn_rcpf(t + 1.f);
}

// async global->LDS, 16B per lane; LDS dest = wave-uniform base + lane*16
__device__ __forceinline__ void g2l16(const void* gp, void* lp) {
  __builtin_amdgcn_global_load_lds(
      reinterpret_cast<__attribute__((address_space(1))) void*>(
          reinterpret_cast<uintptr_t>(gp)),
      reinterpret_cast<__attribute__((address_space(3))) void*>(
          reinterpret_cast<uintptr_t>(lp)),
      16, 0, 0);
}

// ---------------------------------------------------------------------------
// Generic bf16 GEMM, C = A(MxK) * B^T(NxK)^T, tiles BM=BN=128, BK=32,
// 256 threads = 4 waves in 2x2, each wave 64x64 (4x4 MFMA 16x16x32 subtiles).
// LDS layout swizzle: row r's k-chunk kc (8 bf16 = 16B) lives at slot
// kc ^ ((r>>1)&3). Staging loads global chunk (slot ^ swz) into slot; the
// wave's address set is unchanged so global coalescing is intact.
// EPI 0: out(bf16) = tanh(C + bias[n]), row-major ldo
// EPI 1: out(f32)  = (n0<128 ? +C : -C)  -> d_out (dx | dv_H)
// EPI 2: fused A3: per row m, out[m,128+blockIdx.y] += sum_n tanh(C+Ab3)*u[n]
// ---------------------------------------------------------------------------
template <int EPI>
__global__ __launch_bounds__(256) void gemm_bt(
    const bf16_t* __restrict__ A, int lda, const bf16_t* __restrict__ B,
    int ldb, int K, const float* __restrict__ bias, void* __restrict__ outp,
    int ldo, const float* __restrict__ ab3, const float* __restrict__ uvec) {
  constexpr int BM = 128, BN = 128, BK = 32;
  __shared__ __align__(16) bf16_t As[BM * BK];
  __shared__ __align__(16) bf16_t Bs[BN * BK];

  const int m0 = blockIdx.x * BM;
  const int n0 = blockIdx.y * BN;
  const int tid = threadIdx.x;
  const int wave = tid >> 6;
  const int lane = tid & 63;
  const int wm = wave >> 1;  // 2x2 wave grid
  const int wn = wave & 1;

  const int sr = lane >> 2;  // staging row within a 16-row chunk
  // staging: slot (lane&3) must hold global chunk (lane&3) ^ swz(row)
  const int sk = (((lane & 3) ^ ((sr >> 1) & 3)) * 8);
  const int fr = lane & 15;  // fragment m/n index
  // read: want global chunk kc=(lane>>4) -> LDS slot kc ^ swz(fr)
  const int fk = (((lane >> 4) ^ ((fr >> 1) & 3)) * 8);

  f32x4_t acc[4][4] = {};

  for (int k0 = 0; k0 < K; k0 += BK) {
    if (k0) __syncthreads();
#pragma unroll
    for (int t = 0; t < 2; ++t) {
      const int rb = wave * 32 + t * 16;
      g2l16(A + (size_t)(m0 + rb + sr) * lda + (k0 + sk), As + rb * BK);
      g2l16(B + (size_t)(n0 + rb + sr) * ldb + (k0 + sk), Bs + rb * BK);
    }
    __syncthreads();  // drains vmcnt -> tiles visible

    bf16x8_t af[4], bb[4];
#pragma unroll
    for (int t = 0; t < 4; ++t) {
      af[t] = *(const bf16x8_t*)(As + (wm * 64 + t * 16 + fr) * BK + fk);
      bb[t] = *(const bf16x8_t*)(Bs + (wn * 64 + t * 16 + fr) * BK + fk);
    }
#pragma unroll
    for (int i = 0; i < 4; ++i)
#pragma unroll
      for (int j = 0; j < 4; ++j)
        acc[i][j] =
            __builtin_amdgcn_mfma_f32_16x16x32_bf16(af[i], bb[j], acc[i][j], 0, 0, 0);
  }

  // C/D layout (m89-verified): col = lane&15, row = (lane>>4)*4 + reg
  if constexpr (EPI == 0) {
    bf16_t* O = (bf16_t*)outp;
#pragma unroll
    for (int i = 0; i < 4; ++i) {
      const int row = m0 + wm * 64 + i * 16 + (lane >> 4) * 4;
#pragma unroll
      for (int j = 0; j < 4; ++j) {
        const int col = n0 + wn * 64 + j * 16 + fr;
        const float b = bias[col];
#pragma unroll
        for (int r = 0; r < 4; ++r)
          O[(size_t)(row + r) * ldo + col] = (bf16_t)fast_tanh(acc[i][j][r] + b);
      }
    }
  } else if constexpr (EPI == 1) {
    float* O = (float*)outp;
    const float sgn = (n0 >= DIMD) ? -1.f : 1.f;  // dv = -g[:, d:]
#pragma unroll
    for (int i = 0; i < 4; ++i) {
      const int row = m0 + wm * 64 + i * 16 + (lane >> 4) * 4;
#pragma unroll
      for (int j = 0; j < 4; ++j) {
        const int col = n0 + wn * 64 + j * 16 + fr;
#pragma unroll
        for (int r = 0; r < 4; ++r)
          O[(size_t)(row + r) * ldo + col] = sgn * acc[i][j][r];
      }
    }
  } else {
    // fused: out[m, 128+i0] += sum_{j=0..127} tanh(C[m,j] + Ab3[i0*128+j])*u[j]
    __shared__ float red[128];
    __shared__ float us[128];
    __shared__ float a3s[128];
    if (tid < 128) {
      red[tid] = 0.f;
      us[tid] = uvec[tid];
      a3s[tid] = ab3[n0 + tid];
    }
    __syncthreads();
#pragma unroll
    for (int i = 0; i < 4; ++i) {
      float sums[4] = {0.f, 0.f, 0.f, 0.f};
#pragma unroll
      for (int j = 0; j < 4; ++j) {
        const int c = wn * 64 + j * 16 + fr;
        const float uu = us[c];
        const float b3 = a3s[c];
#pragma unroll
        for (int r = 0; r < 4; ++r) sums[r] += fast_tanh(acc[i][j][r] + b3) * uu;
      }
#pragma unroll
      for (int d = 1; d < 16; d <<= 1)
#pragma unroll
        for (int r = 0; r < 4; ++r) sums[r] += __shfl_xor(sums[r], d, 64);
      if (fr == 0) {
        const int rowb = wm * 64 + i * 16 + (lane >> 4) * 4;
#pragma unroll
        for (int r = 0; r < 4; ++r) atomicAdd(&red[rowb + r], sums[r]);
      }
    }
    __syncthreads();
    if (tid < 128) {
      float* O = (float*)outp;
      const size_t idx = (size_t)(m0 + tid) * (2 * DIMD) + DIMD + blockIdx.y;
      O[idx] += red[tid];  // dv_H written earlier by EPI==1 kernel
    }
  }
}

// ---------------------------------------------------------------------------
// merged fp32 -> bf16 straight conversion for inp (1048576 elems) + Hw1 (163840)
// ---------------------------------------------------------------------------
__global__ __launch_bounds__(256) void cvt2(const float4* __restrict__ a,
                                            bf16x4_t* __restrict__ oa, int na4,
                                            const float4* __restrict__ b,
                                            bf16x4_t* __restrict__ ob, int nb4) {
  const int i = blockIdx.x * 256 + threadIdx.x;
  const float4* in;
  bf16x4_t* out;
  int j;
  if (i < na4) {
    in = a; out = oa; j = i;
  } else {
    j = i - na4;
    if (j >= nb4) return;
    in = b; out = ob;
  }
  const float4 v = in[j];
  bf16x4_t o = {(bf16_t)v.x, (bf16_t)v.y, (bf16_t)v.z, (bf16_t)v.w};
  out[j] = o;
}

// fp32 RxC -> bf16 CxR transpose body (dims multiples of 32), 256 threads
__device__ __forceinline__ void tcvt_body(const float* in, bf16_t* out, int R,
                                          int C, int bx, int by) {
  __shared__ float t[32][33];
  const int c0 = bx * 32;
  const int r0 = by * 32;
  const int tx = threadIdx.x & 31;
  const int ty = threadIdx.x >> 5;  // 0..7
#pragma unroll
  for (int k = 0; k < 4; ++k)
    t[ty + k * 8][tx] = in[(size_t)(r0 + ty + k * 8) * C + c0 + tx];
  __syncthreads();
#pragma unroll
  for (int k = 0; k < 4; ++k)
    out[(size_t)(c0 + ty + k * 8) * R + r0 + tx] = (bf16_t)t[tx][ty + k * 8];
}

// big transpose: Aw3 (1024 x 16384)
__global__ __launch_bounds__(256) void tcvt_big(const float* __restrict__ in,
                                                bf16_t* __restrict__ out) {
  tcvt_body(in, out, 1024, 16384, blockIdx.x, blockIdx.y);
}

// merged small transposes: Hw1 (256x640, 160 blk), Aw1 (128x512, 64 blk),
// Aw2 (512x1024, 512 blk) -> 736 blocks
__global__ __launch_bounds__(256) void tcvt_small(
    const float* __restrict__ Hw1, bf16_t* __restrict__ Hw1T,
    const float* __restrict__ Aw1, bf16_t* __restrict__ Aw1T,
    const float* __restrict__ Aw2, bf16_t* __restrict__ Aw2T) {
  int b = blockIdx.x;
  if (b < 160) {
    tcvt_body(Hw1, Hw1T, 256, 640, b % 20, b / 20);
  } else if (b < 224) {
    b -= 160;
    tcvt_body(Aw1, Aw1T, 128, 512, b % 16, b / 16);
  } else {
    b -= 224;
    tcvt_body(Aw2, Aw2T, 512, 1024, b % 32, b / 32);
  }
}

// ---------------------------------------------------------------------------
// per-row: pre2 = h.Hw2, y = tanh(pre2+Hb2), s = 1-y^2,
//          w_j = s * Hw2_j * (1 - h_j^2)    (one wave per row)
// ---------------------------------------------------------------------------
__global__ __launch_bounds__(64) void hgrad_w(const bf16_t* __restrict__ h,
                                              const float* __restrict__ Hw2,
                                              const float* __restrict__ Hb2,
                                              bf16_t* __restrict__ w) {
  const int row = blockIdx.x;
  const int lane = threadIdx.x;
  float hv[10], wv[10];
  float pre2 = 0.f;
#pragma unroll
  for (int t = 0; t < 10; ++t) {
    const int j = lane + t * 64;
    hv[t] = (float)h[(size_t)row * 640 + j];
    wv[t] = Hw2[j];
    pre2 += hv[t] * wv[t];
  }
#pragma unroll
  for (int d = 1; d < 64; d <<= 1) pre2 += __shfl_xor(pre2, d, 64);
  const float y = fast_tanh(pre2 + Hb2[0]);
  const float s = 1.f - y * y;
#pragma unroll
  for (int t = 0; t < 10; ++t) {
    const int j = lane + t * 64;
    w[(size_t)row * 640 + j] = (bf16_t)(s * wv[t] * (1.f - hv[t] * hv[t]));
  }
}

// ---------------------------------------------------------------------------
extern "C" void kernel_launch(void* const* d_in, const int* in_sizes, int n_in,
                              void* d_out, int out_size, void* d_ws,
                              size_t ws_size, hipStream_t stream) {
  (void)in_sizes;
  (void)n_in;
  (void)out_size;
  (void)ws_size;
  // setup_inputs order: t, inp, Hw1, Hb1, Hw2, Hb2, Aw1, Ab1, Aw2, Ab2, Aw3, Ab3, u
  const float* inp = (const float*)d_in[1];
  const float* Hw1 = (const float*)d_in[2];
  const float* Hb1 = (const float*)d_in[3];
  const float* Hw2 = (const float*)d_in[4];
  const float* Hb2 = (const float*)d_in[5];
  const float* Aw1 = (const float*)d_in[6];
  const float* Ab1 = (const float*)d_in[7];
  const float* Aw2 = (const float*)d_in[8];
  const float* Ab2 = (const float*)d_in[9];
  const float* Aw3 = (const float*)d_in[10];
  const float* Ab3 = (const float*)d_in[11];
  const float* u = (const float*)d_in[12];
  float* out = (float*)d_out;

  // workspace layout (~60.5 MB total)
  char* ws = (char*)d_ws;
  bf16_t* inp_bf = (bf16_t*)ws;  ws += (size_t)NROW * 256 * 2;       // 2 MB
  bf16_t* Hw1_bf = (bf16_t*)ws;  ws += (size_t)256 * 640 * 2;        // B^T for H-bwd
  bf16_t* Hw1T = (bf16_t*)ws;    ws += (size_t)640 * 256 * 2;        // B^T for H-fwd
  bf16_t* Aw1T = (bf16_t*)ws;    ws += (size_t)512 * 128 * 2;
  bf16_t* Aw2T = (bf16_t*)ws;    ws += (size_t)1024 * 512 * 2;
  bf16_t* Aw3T = (bf16_t*)ws;    ws += (size_t)16384 * 1024 * 2;     // 32 MB
  bf16_t* h_bf = (bf16_t*)ws;    ws += (size_t)NROW * 640 * 2;
  bf16_t* w_bf = (bf16_t*)ws;    ws += (size_t)NROW * 640 * 2;
  bf16_t* h1_bf = (bf16_t*)ws;   ws += (size_t)NROW * 512 * 2;
  bf16_t* h2_bf = (bf16_t*)ws;   ws += (size_t)NROW * 1024 * 2;

  // ---- conversions (rerun every call: inputs restored each timed launch) ----
  const int na4 = NROW * 256 / 4, nb4 = 256 * 640 / 4;
  cvt2<<<(na4 + nb4 + 255) / 256, 256, 0, stream>>>(
      (const float4*)inp, (bf16x4_t*)inp_bf, na4, (const float4*)Hw1,
      (bf16x4_t*)Hw1_bf, nb4);
  tcvt_small<<<736, 256, 0, stream>>>(Hw1, Hw1T, Aw1, Aw1T, Aw2, Aw2T);
  tcvt_big<<<dim3(16384 / 32, 1024 / 32), 256, 0, stream>>>(Aw3, Aw3T);

  // ---- H net: h = tanh(inp @ Hw1 + Hb1)  (M=4096, K=256, N=640) ----
  gemm_bt<0><<<dim3(32, 5), 256, 0, stream>>>(inp_bf, 256, Hw1T, 256, 256, Hb1,
                                              h_bf, 640, nullptr, nullptr);
  // w_j = s * Hw2_j * (1 - h_j^2)
  hgrad_w<<<NROW, 64, 0, stream>>>(h_bf, Hw2, Hb2, w_bf);
  // g = w @ Hw1^T -> out = [g[:, :128] | -g[:, 128:]]  (M=4096, K=640, N=256)
  gemm_bt<1><<<dim3(32, 2), 256, 0, stream>>>(w_bf, 640, Hw1_bf, 640, 640,
                                              nullptr, out, 256, nullptr, nullptr);

  // ---- A net ----
  // h1 = tanh(x @ Aw1 + Ab1), x = inp[:, :128]  (K=128, N=512)
  gemm_bt<0><<<dim3(32, 4), 256, 0, stream>>>(inp_bf, 256, Aw1T, 128, 128, Ab1,
                                              h1_bf, 512, nullptr, nullptr);
  // h2 = tanh(h1 @ Aw2 + Ab2)  (K=512, N=1024)
  gemm_bt<0><<<dim3(32, 8), 256, 0, stream>>>(h1_bf, 512, Aw2T, 512, 512, Ab2,
                                              h2_bf, 1024, nullptr, nullptr);
  // fused A3: out[:, 128+i0] += sum_j tanh(h2@Aw3 + Ab3)[., i0*128+j] * u[j]
  gemm_bt<2><<<dim3(32, 128), 256, 0, stream>>>(h2_bf, 1024, Aw3T, 1024, 1024,
                                                nullptr, out, 256, Ab3, u);
}

// Round 3
// 277.497 us; speedup vs baseline: 1.3450x; 1.2094x over previous
//
#include <hip/hip_runtime.h>
#include <hip/hip_bf16.h>
#include <cstdint>
#include <cmath>

// ---------------------------------------------------------------------------
// Hamilton_V5: H-net gradient (analytic VJP) + A-net with fused einsum epilogue.
// R3: A3 (95% of FLOPs) moved to MX-fp8 (mfma_scale_f32_32x32x64_f8f6f4) with
//     uniform power-of-2 scales (data stored x64, scale byte 121 = 2^-6 each
//     operand -> exact dequant). A2 writes h2 as fp8 directly; Aw3 transpose
//     emits fp8. H path and small GEMMs stay bf16 MFMA 16x16x32.
// ---------------------------------------------------------------------------

typedef __bf16 bf16_t;
typedef __bf16 bf16x4_t __attribute__((ext_vector_type(4)));
typedef __bf16 bf16x8_t __attribute__((ext_vector_type(8)));
typedef float f32x4_t __attribute__((ext_vector_type(4)));
typedef float f32x16_t __attribute__((ext_vector_type(16)));
typedef int intx4_t __attribute__((ext_vector_type(4)));
typedef int intx8_t __attribute__((ext_vector_type(8)));

#define DIMD 128
#define NROW 4096

// branchless tanh: t=2^(2x*log2e); tanh=1-2/(t+1). Saturates correctly at +-inf.
__device__ __forceinline__ float fast_tanh(float x) {
  float t = __builtin_amdgcn_exp2f(x * 2.8853900817779268f);
  return 1.f - 2.f * __builtin_amdgcn_rcpf(t + 1.f);
}

// f32 -> fp8 e4m3 (OCP), RNE+sat via HW cvt
__device__ __forceinline__ uint8_t to_fp8(float x) {
  return (uint8_t)(__builtin_amdgcn_cvt_pk_fp8_f32(x, x, 0, false) & 0xff);
}

// async global->LDS, 16B per lane; LDS dest = wave-uniform base + lane*16
__device__ __forceinline__ void g2l16(const void* gp, void* lp) {
  __builtin_amdgcn_global_load_lds(
      reinterpret_cast<__attribute__((address_space(1))) void*>(
          reinterpret_cast<uintptr_t>(gp)),
      reinterpret_cast<__attribute__((address_space(3))) void*>(
          reinterpret_cast<uintptr_t>(lp)),
      16, 0, 0);
}

// ---------------------------------------------------------------------------
// bf16 GEMM, C = A(MxK) * B^T(NxK)^T, 128x128x32 tiles, 4 waves 2x2.
// LDS swizzle: row r's 16B k-chunk kc lives at slot kc ^ ((r>>1)&3).
// EPI 0: out(bf16) = tanh(C + bias[n])
// EPI 1: out(f32)  = (n0<128 ? +C : -C)  -> d_out (dx | dv_H)
// EPI 3: out(fp8)  = fp8( 64 * tanh(C + bias[n]) )   (h2 for the fp8 A3)
// ---------------------------------------------------------------------------
template <int EPI>
__global__ __launch_bounds__(256) void gemm_bt(
    const bf16_t* __restrict__ A, int lda, const bf16_t* __restrict__ B,
    int ldb, int K, const float* __restrict__ bias, void* __restrict__ outp,
    int ldo) {
  constexpr int BM = 128, BN = 128, BK = 32;
  __shared__ __align__(16) bf16_t As[BM * BK];
  __shared__ __align__(16) bf16_t Bs[BN * BK];

  const int m0 = blockIdx.x * BM;
  const int n0 = blockIdx.y * BN;
  const int tid = threadIdx.x;
  const int wave = tid >> 6;
  const int lane = tid & 63;
  const int wm = wave >> 1;
  const int wn = wave & 1;

  const int sr = lane >> 2;
  const int sk = (((lane & 3) ^ ((sr >> 1) & 3)) * 8);
  const int fr = lane & 15;
  const int fk = (((lane >> 4) ^ ((fr >> 1) & 3)) * 8);

  f32x4_t acc[4][4] = {};

  for (int k0 = 0; k0 < K; k0 += BK) {
    if (k0) __syncthreads();
#pragma unroll
    for (int t = 0; t < 2; ++t) {
      const int rb = wave * 32 + t * 16;
      g2l16(A + (size_t)(m0 + rb + sr) * lda + (k0 + sk), As + rb * BK);
      g2l16(B + (size_t)(n0 + rb + sr) * ldb + (k0 + sk), Bs + rb * BK);
    }
    __syncthreads();

    bf16x8_t af[4], bb[4];
#pragma unroll
    for (int t = 0; t < 4; ++t) {
      af[t] = *(const bf16x8_t*)(As + (wm * 64 + t * 16 + fr) * BK + fk);
      bb[t] = *(const bf16x8_t*)(Bs + (wn * 64 + t * 16 + fr) * BK + fk);
    }
#pragma unroll
    for (int i = 0; i < 4; ++i)
#pragma unroll
      for (int j = 0; j < 4; ++j)
        acc[i][j] =
            __builtin_amdgcn_mfma_f32_16x16x32_bf16(af[i], bb[j], acc[i][j], 0, 0, 0);
  }

  // C/D layout (m89): col = lane&15, row = (lane>>4)*4 + reg
  if constexpr (EPI == 0) {
    bf16_t* O = (bf16_t*)outp;
#pragma unroll
    for (int i = 0; i < 4; ++i) {
      const int row = m0 + wm * 64 + i * 16 + (lane >> 4) * 4;
#pragma unroll
      for (int j = 0; j < 4; ++j) {
        const int col = n0 + wn * 64 + j * 16 + fr;
        const float b = bias[col];
#pragma unroll
        for (int r = 0; r < 4; ++r)
          O[(size_t)(row + r) * ldo + col] = (bf16_t)fast_tanh(acc[i][j][r] + b);
      }
    }
  } else if constexpr (EPI == 1) {
    float* O = (float*)outp;
    const float sgn = (n0 >= DIMD) ? -1.f : 1.f;  // dv = -g[:, d:]
#pragma unroll
    for (int i = 0; i < 4; ++i) {
      const int row = m0 + wm * 64 + i * 16 + (lane >> 4) * 4;
#pragma unroll
      for (int j = 0; j < 4; ++j) {
        const int col = n0 + wn * 64 + j * 16 + fr;
#pragma unroll
        for (int r = 0; r < 4; ++r)
          O[(size_t)(row + r) * ldo + col] = sgn * acc[i][j][r];
      }
    }
  } else {  // EPI 3: fp8 x64 output
    uint8_t* O = (uint8_t*)outp;
#pragma unroll
    for (int i = 0; i < 4; ++i) {
      const int row = m0 + wm * 64 + i * 16 + (lane >> 4) * 4;
#pragma unroll
      for (int j = 0; j < 4; ++j) {
        const int col = n0 + wn * 64 + j * 16 + fr;
        const float b = bias[col];
#pragma unroll
        for (int r = 0; r < 4; ++r)
          O[(size_t)(row + r) * ldo + col] =
              to_fp8(64.f * fast_tanh(acc[i][j][r] + b));
      }
    }
  }
}

// ---------------------------------------------------------------------------
// A3 fused GEMM in MX-fp8: C = h2(4096x1024) @ Aw3T(16384x1024)^T, then
// out[m, 128+by] += sum_n tanh(C[m,n]+Ab3[n]) * u[n&127].
// Data stored x64; both scale operands 2^-6 (e8m0 byte 121) -> exact dequant.
// 128x128 tile, BK=64 bytes, 2x2 waves, each 64x64 via 2x2 mfma 32x32x64.
// LDS rows 64B = 4 chunks of 16B; chunk kc of row r at slot kc ^ ((r>>1)&3)
// -> staging (16 rows/wave-instr) and both fragment b128 reads conflict-free.
// ---------------------------------------------------------------------------
__global__ __launch_bounds__(256) void gemm_a3_fp8(
    const uint8_t* __restrict__ A, const uint8_t* __restrict__ B,
    float* __restrict__ out, const float* __restrict__ ab3,
    const float* __restrict__ uvec) {
  constexpr int BK = 64, K = 1024;
  __shared__ __align__(16) uint8_t As[128 * BK];
  __shared__ __align__(16) uint8_t Bs[128 * BK];
  __shared__ float red[128], us[128], a3s[128];

  const int m0 = blockIdx.x * 128;
  const int n0 = blockIdx.y * 128;
  const int tid = threadIdx.x;
  const int wave = tid >> 6;
  const int lane = tid & 63;
  const int wm = wave >> 1;
  const int wn = wave & 1;

  if (tid < 128) {
    red[tid] = 0.f;
    us[tid] = uvec[tid];
    a3s[tid] = ab3[n0 + tid];
  }

  // staging: lane -> row sr=lane>>2 (of 16), slot lane&3 holds global chunk
  // (lane&3) ^ ((sr>>1)&3)
  const int sr = lane >> 2;
  const int sk = ((lane & 3) ^ ((sr >> 1) & 3)) * 16;

  // fragments: tile row r = (wm|wn)*64 + i*32 + (lane&31); k-chunk c0=lane>>5
  // covers global chunks {2c0, 2c0+1} at slots (2c0)^w, (2c0+1)^w, w=((lane&31)>>1)&3
  const int rl = lane & 31;
  const int w = (rl >> 1) & 3;
  const int c0 = lane >> 5;
  const int sLo = ((2 * c0) ^ w) * 16;
  const int sHi = ((2 * c0 + 1) ^ w) * 16;

  f32x16_t acc[2][2] = {};

  for (int k0 = 0; k0 < K; k0 += BK) {
    if (k0) __syncthreads();
#pragma unroll
    for (int t = 0; t < 2; ++t) {
      const int rb = t * 64 + wave * 16;  // 16 rows per wave-instr
      g2l16(A + (size_t)(m0 + rb + sr) * K + (k0 + sk), As + rb * BK);
      g2l16(B + (size_t)(n0 + rb + sr) * K + (k0 + sk), Bs + rb * BK);
    }
    __syncthreads();

    intx8_t af[2], bf[2];
#pragma unroll
    for (int i = 0; i < 2; ++i) {
      const int ra = (wm * 64 + i * 32 + rl) * BK;
      intx4_t lo = *(const intx4_t*)(As + ra + sLo);
      intx4_t hi = *(const intx4_t*)(As + ra + sHi);
      af[i] = __builtin_shufflevector(lo, hi, 0, 1, 2, 3, 4, 5, 6, 7);
      const int rb = (wn * 64 + i * 32 + rl) * BK;
      intx4_t lob = *(const intx4_t*)(Bs + rb + sLo);
      intx4_t hib = *(const intx4_t*)(Bs + rb + sHi);
      bf[i] = __builtin_shufflevector(lob, hib, 0, 1, 2, 3, 4, 5, 6, 7);
    }
#pragma unroll
    for (int i = 0; i < 2; ++i)
#pragma unroll
      for (int j = 0; j < 2; ++j)
        acc[i][j] = __builtin_amdgcn_mfma_scale_f32_32x32x64_f8f6f4(
            af[i], bf[j], acc[i][j], 0 /*fp8 A*/, 0 /*fp8 B*/,
            0, 0x79797979 /*2^-6*/, 0, 0x79797979 /*2^-6*/);
  }

  // C/D (m74/m101): col = lane&31, row = (reg&3) + 8*(reg>>2) + 4*(lane>>5)
  const int q = lane >> 5;
#pragma unroll
  for (int i = 0; i < 2; ++i) {
    float sums[16];
#pragma unroll
    for (int r = 0; r < 16; ++r) sums[r] = 0.f;
#pragma unroll
    for (int j = 0; j < 2; ++j) {
      const int c = wn * 64 + j * 32 + rl;
      const float uu = us[c];
      const float b3 = a3s[c];
#pragma unroll
      for (int r = 0; r < 16; ++r)
        sums[r] += fast_tanh(acc[i][j][r] + b3) * uu;
    }
#pragma unroll
    for (int d = 1; d < 32; d <<= 1)
#pragma unroll
      for (int r = 0; r < 16; ++r) sums[r] += __shfl_xor(sums[r], d, 64);
    if (rl == 0) {
      const int rowb = wm * 64 + i * 32 + 4 * q;
#pragma unroll
      for (int r = 0; r < 16; ++r)
        atomicAdd(&red[rowb + (r & 3) + 8 * (r >> 2)], sums[r]);
    }
  }
  __syncthreads();
  if (tid < 128) {
    const size_t idx = (size_t)(m0 + tid) * (2 * DIMD) + DIMD + blockIdx.y;
    out[idx] += red[tid];  // dv_H written earlier by EPI==1 kernel
  }
}

// ---------------------------------------------------------------------------
// merged fp32 -> bf16 straight conversion for inp + Hw1
// ---------------------------------------------------------------------------
__global__ __launch_bounds__(256) void cvt2(const float4* __restrict__ a,
                                            bf16x4_t* __restrict__ oa, int na4,
                                            const float4* __restrict__ b,
                                            bf16x4_t* __restrict__ ob, int nb4) {
  const int i = blockIdx.x * 256 + threadIdx.x;
  const float4* in;
  bf16x4_t* out;
  int j;
  if (i < na4) {
    in = a; out = oa; j = i;
  } else {
    j = i - na4;
    if (j >= nb4) return;
    in = b; out = ob;
  }
  const float4 v = in[j];
  bf16x4_t o = {(bf16_t)v.x, (bf16_t)v.y, (bf16_t)v.z, (bf16_t)v.w};
  out[j] = o;
}

// fp32 RxC -> bf16 CxR transpose body (dims multiples of 32), 256 threads
__device__ __forceinline__ void tcvt_body(const float* in, bf16_t* out, int R,
                                          int C, int bx, int by) {
  __shared__ float t[32][33];
  const int c0 = bx * 32;
  const int r0 = by * 32;
  const int tx = threadIdx.x & 31;
  const int ty = threadIdx.x >> 5;
#pragma unroll
  for (int k = 0; k < 4; ++k)
    t[ty + k * 8][tx] = in[(size_t)(r0 + ty + k * 8) * C + c0 + tx];
  __syncthreads();
#pragma unroll
  for (int k = 0; k < 4; ++k)
    out[(size_t)(c0 + ty + k * 8) * R + r0 + tx] = (bf16_t)t[tx][ty + k * 8];
}

// big transpose: Aw3 (1024 x 16384) -> fp8 x64, transposed (16384 x 1024)
__global__ __launch_bounds__(256) void tcvt_big_fp8(const float* __restrict__ in,
                                                    uint8_t* __restrict__ out) {
  __shared__ float t[32][33];
  const int c0 = blockIdx.x * 32;
  const int r0 = blockIdx.y * 32;
  const int tx = threadIdx.x & 31;
  const int ty = threadIdx.x >> 5;
#pragma unroll
  for (int k = 0; k < 4; ++k)
    t[ty + k * 8][tx] = in[(size_t)(r0 + ty + k * 8) * 16384 + c0 + tx];
  __syncthreads();
#pragma unroll
  for (int k = 0; k < 4; ++k)
    out[(size_t)(c0 + ty + k * 8) * 1024 + r0 + tx] =
        to_fp8(64.f * t[tx][ty + k * 8]);
}

// merged small transposes: Hw1 (256x640), Aw1 (128x512), Aw2 (512x1024)
__global__ __launch_bounds__(256) void tcvt_small(
    const float* __restrict__ Hw1, bf16_t* __restrict__ Hw1T,
    const float* __restrict__ Aw1, bf16_t* __restrict__ Aw1T,
    const float* __restrict__ Aw2, bf16_t* __restrict__ Aw2T) {
  int b = blockIdx.x;
  if (b < 160) {
    tcvt_body(Hw1, Hw1T, 256, 640, b % 20, b / 20);
  } else if (b < 224) {
    b -= 160;
    tcvt_body(Aw1, Aw1T, 128, 512, b % 16, b / 16);
  } else {
    b -= 224;
    tcvt_body(Aw2, Aw2T, 512, 1024, b % 32, b / 32);
  }
}

// ---------------------------------------------------------------------------
// per-row: pre2 = h.Hw2, y = tanh(pre2+Hb2), s = 1-y^2,
//          w_j = s * Hw2_j * (1 - h_j^2)    (one wave per row)
// ---------------------------------------------------------------------------
__global__ __launch_bounds__(64) void hgrad_w(const bf16_t* __restrict__ h,
                                              const float* __restrict__ Hw2,
                                              const float* __restrict__ Hb2,
                                              bf16_t* __restrict__ w) {
  const int row = blockIdx.x;
  const int lane = threadIdx.x;
  float hv[10], wv[10];
  float pre2 = 0.f;
#pragma unroll
  for (int t = 0; t < 10; ++t) {
    const int j = lane + t * 64;
    hv[t] = (float)h[(size_t)row * 640 + j];
    wv[t] = Hw2[j];
    pre2 += hv[t] * wv[t];
  }
#pragma unroll
  for (int d = 1; d < 64; d <<= 1) pre2 += __shfl_xor(pre2, d, 64);
  const float y = fast_tanh(pre2 + Hb2[0]);
  const float s = 1.f - y * y;
#pragma unroll
  for (int t = 0; t < 10; ++t) {
    const int j = lane + t * 64;
    w[(size_t)row * 640 + j] = (bf16_t)(s * wv[t] * (1.f - hv[t] * hv[t]));
  }
}

// ---------------------------------------------------------------------------
extern "C" void kernel_launch(void* const* d_in, const int* in_sizes, int n_in,
                              void* d_out, int out_size, void* d_ws,
                              size_t ws_size, hipStream_t stream) {
  (void)in_sizes;
  (void)n_in;
  (void)out_size;
  (void)ws_size;
  // order: t, inp, Hw1, Hb1, Hw2, Hb2, Aw1, Ab1, Aw2, Ab2, Aw3, Ab3, u
  const float* inp = (const float*)d_in[1];
  const float* Hw1 = (const float*)d_in[2];
  const float* Hb1 = (const float*)d_in[3];
  const float* Hw2 = (const float*)d_in[4];
  const float* Hb2 = (const float*)d_in[5];
  const float* Aw1 = (const float*)d_in[6];
  const float* Ab1 = (const float*)d_in[7];
  const float* Aw2 = (const float*)d_in[8];
  const float* Ab2 = (const float*)d_in[9];
  const float* Aw3 = (const float*)d_in[10];
  const float* Ab3 = (const float*)d_in[11];
  const float* u = (const float*)d_in[12];
  float* out = (float*)d_out;

  // workspace layout (~38 MB)
  char* ws = (char*)d_ws;
  bf16_t* inp_bf = (bf16_t*)ws;   ws += (size_t)NROW * 256 * 2;
  bf16_t* Hw1_bf = (bf16_t*)ws;   ws += (size_t)256 * 640 * 2;
  bf16_t* Hw1T = (bf16_t*)ws;     ws += (size_t)640 * 256 * 2;
  bf16_t* Aw1T = (bf16_t*)ws;     ws += (size_t)512 * 128 * 2;
  bf16_t* Aw2T = (bf16_t*)ws;     ws += (size_t)1024 * 512 * 2;
  uint8_t* Aw3T8 = (uint8_t*)ws;  ws += (size_t)16384 * 1024;   // fp8 x64
  bf16_t* h_bf = (bf16_t*)ws;     ws += (size_t)NROW * 640 * 2;
  bf16_t* w_bf = (bf16_t*)ws;     ws += (size_t)NROW * 640 * 2;
  bf16_t* h1_bf = (bf16_t*)ws;    ws += (size_t)NROW * 512 * 2;
  uint8_t* h2_f8 = (uint8_t*)ws;  ws += (size_t)NROW * 1024;    // fp8 x64

  // ---- conversions ----
  const int na4 = NROW * 256 / 4, nb4 = 256 * 640 / 4;
  cvt2<<<(na4 + nb4 + 255) / 256, 256, 0, stream>>>(
      (const float4*)inp, (bf16x4_t*)inp_bf, na4, (const float4*)Hw1,
      (bf16x4_t*)Hw1_bf, nb4);
  tcvt_small<<<736, 256, 0, stream>>>(Hw1, Hw1T, Aw1, Aw1T, Aw2, Aw2T);
  tcvt_big_fp8<<<dim3(16384 / 32, 1024 / 32), 256, 0, stream>>>(Aw3, Aw3T8);

  // ---- H net ----
  gemm_bt<0><<<dim3(32, 5), 256, 0, stream>>>(inp_bf, 256, Hw1T, 256, 256, Hb1,
                                              h_bf, 640);
  hgrad_w<<<NROW, 64, 0, stream>>>(h_bf, Hw2, Hb2, w_bf);
  gemm_bt<1><<<dim3(32, 2), 256, 0, stream>>>(w_bf, 640, Hw1_bf, 640, 640,
                                              nullptr, out, 256);

  // ---- A net ----
  gemm_bt<0><<<dim3(32, 4), 256, 0, stream>>>(inp_bf, 256, Aw1T, 128, 128, Ab1,
                                              h1_bf, 512);
  // h2 -> fp8 x64 directly
  gemm_bt<3><<<dim3(32, 8), 256, 0, stream>>>(h1_bf, 512, Aw2T, 512, 512, Ab2,
                                              h2_f8, 1024);
  // fused A3 in MX-fp8
  gemm_a3_fp8<<<dim3(32, 128), 256, 0, stream>>>(h2_f8, Aw3T8, out, Ab3, u);
}

// Round 4
// 277.185 us; speedup vs baseline: 1.3466x; 1.0011x over previous
//
#include <hip/hip_runtime.h>
#include <hip/hip_bf16.h>
#include <cstdint>
#include <cmath>

// ---------------------------------------------------------------------------
// Hamilton_V5: H-net gradient (analytic VJP) + A-net with fused einsum epilogue.
// R4: A3 fp8 kernel gets fragment-ordered LDS staging (conflict-free under the
//     stride-4 phase model identified from R2/R3 counter evidence) + BK=128
//     (half the barrier drains; LDS 34 KB keeps ~3 blocks/CU). Prep kernels
//     merged into one launch.
// ---------------------------------------------------------------------------

typedef __bf16 bf16_t;
typedef __bf16 bf16x4_t __attribute__((ext_vector_type(4)));
typedef __bf16 bf16x8_t __attribute__((ext_vector_type(8)));
typedef float f32x4_t __attribute__((ext_vector_type(4)));
typedef float f32x16_t __attribute__((ext_vector_type(16)));
typedef int intx4_t __attribute__((ext_vector_type(4)));
typedef int intx8_t __attribute__((ext_vector_type(8)));

#define DIMD 128
#define NROW 4096

// branchless tanh: t=2^(2x*log2e); tanh=1-2/(t+1). Saturates correctly at +-inf.
__device__ __forceinline__ float fast_tanh(float x) {
  float t = __builtin_amdgcn_exp2f(x * 2.8853900817779268f);
  return 1.f - 2.f * __builtin_amdgcn_rcpf(t + 1.f);
}

// f32 -> fp8 e4m3 (OCP), RNE+sat via HW cvt
__device__ __forceinline__ uint8_t to_fp8(float x) {
  return (uint8_t)(__builtin_amdgcn_cvt_pk_fp8_f32(x, x, 0, false) & 0xff);
}

// async global->LDS, 16B per lane; LDS dest = wave-uniform base + lane*16
__device__ __forceinline__ void g2l16(const void* gp, void* lp) {
  __builtin_amdgcn_global_load_lds(
      reinterpret_cast<__attribute__((address_space(1))) void*>(
          reinterpret_cast<uintptr_t>(gp)),
      reinterpret_cast<__attribute__((address_space(3))) void*>(
          reinterpret_cast<uintptr_t>(lp)),
      16, 0, 0);
}

// ---------------------------------------------------------------------------
// bf16 GEMM, C = A(MxK) * B^T(NxK)^T, 128x128x32 tiles, 4 waves 2x2.
// LDS swizzle: row r's 16B k-chunk kc lives at slot kc ^ ((r>>1)&3).
// EPI 0: out(bf16) = tanh(C + bias[n])
// EPI 1: out(f32)  = (n0<128 ? +C : -C)  -> d_out (dx | dv_H)
// EPI 3: out(fp8)  = fp8( 64 * tanh(C + bias[n]) )   (h2 for the fp8 A3)
// ---------------------------------------------------------------------------
template <int EPI>
__global__ __launch_bounds__(256) void gemm_bt(
    const bf16_t* __restrict__ A, int lda, const bf16_t* __restrict__ B,
    int ldb, int K, const float* __restrict__ bias, void* __restrict__ outp,
    int ldo) {
  constexpr int BM = 128, BN = 128, BK = 32;
  __shared__ __align__(16) bf16_t As[BM * BK];
  __shared__ __align__(16) bf16_t Bs[BN * BK];

  const int m0 = blockIdx.x * BM;
  const int n0 = blockIdx.y * BN;
  const int tid = threadIdx.x;
  const int wave = tid >> 6;
  const int lane = tid & 63;
  const int wm = wave >> 1;
  const int wn = wave & 1;

  const int sr = lane >> 2;
  const int sk = (((lane & 3) ^ ((sr >> 1) & 3)) * 8);
  const int fr = lane & 15;
  const int fk = (((lane >> 4) ^ ((fr >> 1) & 3)) * 8);

  f32x4_t acc[4][4] = {};

  for (int k0 = 0; k0 < K; k0 += BK) {
    if (k0) __syncthreads();
#pragma unroll
    for (int t = 0; t < 2; ++t) {
      const int rb = wave * 32 + t * 16;
      g2l16(A + (size_t)(m0 + rb + sr) * lda + (k0 + sk), As + rb * BK);
      g2l16(B + (size_t)(n0 + rb + sr) * ldb + (k0 + sk), Bs + rb * BK);
    }
    __syncthreads();

    bf16x8_t af[4], bb[4];
#pragma unroll
    for (int t = 0; t < 4; ++t) {
      af[t] = *(const bf16x8_t*)(As + (wm * 64 + t * 16 + fr) * BK + fk);
      bb[t] = *(const bf16x8_t*)(Bs + (wn * 64 + t * 16 + fr) * BK + fk);
    }
#pragma unroll
    for (int i = 0; i < 4; ++i)
#pragma unroll
      for (int j = 0; j < 4; ++j)
        acc[i][j] =
            __builtin_amdgcn_mfma_f32_16x16x32_bf16(af[i], bb[j], acc[i][j], 0, 0, 0);
  }

  // C/D layout (m89): col = lane&15, row = (lane>>4)*4 + reg
  if constexpr (EPI == 0) {
    bf16_t* O = (bf16_t*)outp;
#pragma unroll
    for (int i = 0; i < 4; ++i) {
      const int row = m0 + wm * 64 + i * 16 + (lane >> 4) * 4;
#pragma unroll
      for (int j = 0; j < 4; ++j) {
        const int col = n0 + wn * 64 + j * 16 + fr;
        const float b = bias[col];
#pragma unroll
        for (int r = 0; r < 4; ++r)
          O[(size_t)(row + r) * ldo + col] = (bf16_t)fast_tanh(acc[i][j][r] + b);
      }
    }
  } else if constexpr (EPI == 1) {
    float* O = (float*)outp;
    const float sgn = (n0 >= DIMD) ? -1.f : 1.f;  // dv = -g[:, d:]
#pragma unroll
    for (int i = 0; i < 4; ++i) {
      const int row = m0 + wm * 64 + i * 16 + (lane >> 4) * 4;
#pragma unroll
      for (int j = 0; j < 4; ++j) {
        const int col = n0 + wn * 64 + j * 16 + fr;
#pragma unroll
        for (int r = 0; r < 4; ++r)
          O[(size_t)(row + r) * ldo + col] = sgn * acc[i][j][r];
      }
    }
  } else {  // EPI 3: fp8 x64 output
    uint8_t* O = (uint8_t*)outp;
#pragma unroll
    for (int i = 0; i < 4; ++i) {
      const int row = m0 + wm * 64 + i * 16 + (lane >> 4) * 4;
#pragma unroll
      for (int j = 0; j < 4; ++j) {
        const int col = n0 + wn * 64 + j * 16 + fr;
        const float b = bias[col];
#pragma unroll
        for (int r = 0; r < 4; ++r)
          O[(size_t)(row + r) * ldo + col] =
              to_fp8(64.f * fast_tanh(acc[i][j][r] + b));
      }
    }
  }
}

// ---------------------------------------------------------------------------
// A3 fused GEMM in MX-fp8: C = h2(4096x1024) @ Aw3T(16384x1024)^T, then
// out[m, 128+by] += sum_n tanh(C[m,n]+Ab3[n]) * u[n&127].
// Data stored x64; both scales 2^-6 (e8m0 byte 121) -> exact dequant.
// 128x128 tile, BK=128 bytes (2 MFMA k-steps/iter), 2x2 waves, each 64x64 via
// 2x2 mfma 32x32x64.
// LDS is FRAGMENT-ORDERED: 1KB region per (k-step ks, row-group rG, k-half c0);
// within a region, lane rl's 16B half h sits at slot
//   S(rl,h) = ((2(rl&3) + (rl>>2) + h)&7) + 8(rl>>2)
// -> every 8-lane phase (consecutive OR stride-4) covers all 8 bank groups.
// The DMA inverse map scrambles the per-lane GLOBAL addresses instead (same
// address set per wave -> coalescing unchanged); LDS writes stay lane-linear.
// ---------------------------------------------------------------------------
__global__ __launch_bounds__(256) void gemm_a3_fp8(
    const uint8_t* __restrict__ A, const uint8_t* __restrict__ B,
    float* __restrict__ out, const float* __restrict__ ab3,
    const float* __restrict__ uvec) {
  constexpr int K = 1024, BK = 128, KS = BK / 64;
  __shared__ __align__(16) uint8_t As[16384];
  __shared__ __align__(16) uint8_t Bs[16384];
  __shared__ float red[128], us[128], a3s[128];

  const int m0 = blockIdx.x * 128;
  const int n0 = blockIdx.y * 128;
  const int tid = threadIdx.x;
  const int wave = tid >> 6;
  const int lane = tid & 63;
  const int wm = wave >> 1;
  const int wn = wave & 1;
  const int rl = lane & 31;
  const int c0 = lane >> 5;

  if (tid < 128) {
    red[tid] = 0.f;
    us[tid] = uvec[tid];
    a3s[tid] = ab3[n0 + tid];
  }

  // staging inverse map: DMA lane d writes region slot d; slot s holds
  // (rl = 4*(s>>3) + q>>1, h = q&1) with q = ((s&7) - (s>>3)) & 7
  const int sb = lane >> 3;
  const int sq = ((lane & 7) - sb) & 7;
  const int s_rl = sb * 4 + (sq >> 1);
  const int s_h = sq & 1;
  const size_t aRow = (size_t)(m0 + wave * 32 + s_rl) * K + s_h * 16;  // rG=wave
  const size_t bRow = (size_t)(n0 + wave * 32 + s_rl) * K + s_h * 16;

  // fragment read byte offsets within a region (h = 0, 1)
  const int f0 = ((((2 * (rl & 3) + (rl >> 2)) & 7) + ((rl >> 2) << 3)) << 4);
  const int f1 =
      ((((2 * (rl & 3) + (rl >> 2) + 1) & 7) + ((rl >> 2) << 3)) << 4);

  f32x16_t acc[2][2] = {};

  for (int k0 = 0; k0 < K; k0 += BK) {
    if (k0) __syncthreads();
#pragma unroll
    for (int ks = 0; ks < KS; ++ks)
#pragma unroll
      for (int cc = 0; cc < 2; ++cc) {
        const int rbase = ((ks * 4 + wave) * 2 + cc) * 1024;
        const int gofs = k0 + ks * 64 + cc * 32;
        g2l16(A + aRow + gofs, As + rbase);
        g2l16(B + bRow + gofs, Bs + rbase);
      }
    __syncthreads();

#pragma unroll
    for (int ks = 0; ks < KS; ++ks) {
      intx8_t af[2], bf[2];
#pragma unroll
      for (int i = 0; i < 2; ++i) {
        const int ra = ((ks * 4 + (wm * 2 + i)) * 2 + c0) * 1024;
        intx4_t lo = *(const intx4_t*)(As + ra + f0);
        intx4_t hi = *(const intx4_t*)(As + ra + f1);
        af[i] = __builtin_shufflevector(lo, hi, 0, 1, 2, 3, 4, 5, 6, 7);
        const int rb = ((ks * 4 + (wn * 2 + i)) * 2 + c0) * 1024;
        intx4_t lob = *(const intx4_t*)(Bs + rb + f0);
        intx4_t hib = *(const intx4_t*)(Bs + rb + f1);
        bf[i] = __builtin_shufflevector(lob, hib, 0, 1, 2, 3, 4, 5, 6, 7);
      }
#pragma unroll
      for (int i = 0; i < 2; ++i)
#pragma unroll
        for (int j = 0; j < 2; ++j)
          acc[i][j] = __builtin_amdgcn_mfma_scale_f32_32x32x64_f8f6f4(
              af[i], bf[j], acc[i][j], 0 /*fp8 A*/, 0 /*fp8 B*/,
              0, 0x79797979 /*2^-6*/, 0, 0x79797979 /*2^-6*/);
    }
  }

  // C/D (m74/m101): col = lane&31, row = (reg&3) + 8*(reg>>2) + 4*(lane>>5)
  const int q = lane >> 5;
#pragma unroll
  for (int i = 0; i < 2; ++i) {
    float sums[16];
#pragma unroll
    for (int r = 0; r < 16; ++r) sums[r] = 0.f;
#pragma unroll
    for (int j = 0; j < 2; ++j) {
      const int c = wn * 64 + j * 32 + rl;
      const float uu = us[c];
      const float b3 = a3s[c];
#pragma unroll
      for (int r = 0; r < 16; ++r)
        sums[r] += fast_tanh(acc[i][j][r] + b3) * uu;
    }
#pragma unroll
    for (int d = 1; d < 32; d <<= 1)
#pragma unroll
      for (int r = 0; r < 16; ++r) sums[r] += __shfl_xor(sums[r], d, 64);
    if (rl == 0) {
      const int rowb = wm * 64 + i * 32 + 4 * q;
#pragma unroll
      for (int r = 0; r < 16; ++r)
        atomicAdd(&red[rowb + (r & 3) + 8 * (r >> 2)], sums[r]);
    }
  }
  __syncthreads();
  if (tid < 128) {
    const size_t idx = (size_t)(m0 + tid) * (2 * DIMD) + DIMD + blockIdx.y;
    out[idx] += red[tid];  // dv_H written earlier by EPI==1 kernel
  }
}

// ---------------------------------------------------------------------------
// merged prep: big fp8 transpose (16384 blk) + cvt (1184 blk) + small
// transposes (736 blk)
// ---------------------------------------------------------------------------
__device__ __forceinline__ void tcvt_body(const float* in, bf16_t* out, int R,
                                          int C, int bx, int by) {
  __shared__ float t[32][33];
  const int c0 = bx * 32;
  const int r0 = by * 32;
  const int tx = threadIdx.x & 31;
  const int ty = threadIdx.x >> 5;
#pragma unroll
  for (int k = 0; k < 4; ++k)
    t[ty + k * 8][tx] = in[(size_t)(r0 + ty + k * 8) * C + c0 + tx];
  __syncthreads();
#pragma unroll
  for (int k = 0; k < 4; ++k)
    out[(size_t)(c0 + ty + k * 8) * R + r0 + tx] = (bf16_t)t[tx][ty + k * 8];
}

__global__ __launch_bounds__(256) void prep(
    const float* __restrict__ inp, bf16_t* __restrict__ inp_bf,
    const float* __restrict__ Hw1, bf16_t* __restrict__ Hw1_bf,
    bf16_t* __restrict__ Hw1T, const float* __restrict__ Aw1,
    bf16_t* __restrict__ Aw1T, const float* __restrict__ Aw2,
    bf16_t* __restrict__ Aw2T, const float* __restrict__ Aw3,
    uint8_t* __restrict__ Aw3T8) {
  int b = blockIdx.x;
  if (b < 16384) {
    // Aw3 (1024 x 16384) -> fp8 x64, transposed (16384 x 1024)
    __shared__ float t[32][33];
    const int c0 = (b & 511) * 32;
    const int r0 = (b >> 9) * 32;
    const int tx = threadIdx.x & 31;
    const int ty = threadIdx.x >> 5;
#pragma unroll
    for (int k = 0; k < 4; ++k)
      t[ty + k * 8][tx] = Aw3[(size_t)(r0 + ty + k * 8) * 16384 + c0 + tx];
    __syncthreads();
#pragma unroll
    for (int k = 0; k < 4; ++k)
      Aw3T8[(size_t)(c0 + ty + k * 8) * 1024 + r0 + tx] =
          to_fp8(64.f * t[tx][ty + k * 8]);
  } else if (b < 16384 + 1184) {
    // straight conversions: inp (262144 float4) then Hw1 (40960 float4)
    const int i = (b - 16384) * 256 + threadIdx.x;
    const int na4 = NROW * 256 / 4;
    const float4* in;
    bf16x4_t* out;
    int j;
    if (i < na4) {
      in = (const float4*)inp; out = (bf16x4_t*)inp_bf; j = i;
    } else {
      j = i - na4;
      if (j >= 256 * 640 / 4) return;
      in = (const float4*)Hw1; out = (bf16x4_t*)Hw1_bf;
    }
    const float4 v = in[j];
    bf16x4_t o = {(bf16_t)v.x, (bf16_t)v.y, (bf16_t)v.z, (bf16_t)v.w};
    out[j] = o;
  } else {
    int s = b - (16384 + 1184);
    if (s < 160) {
      tcvt_body(Hw1, Hw1T, 256, 640, s % 20, s / 20);
    } else if (s < 224) {
      s -= 160;
      tcvt_body(Aw1, Aw1T, 128, 512, s % 16, s / 16);
    } else {
      s -= 224;
      tcvt_body(Aw2, Aw2T, 512, 1024, s % 32, s / 32);
    }
  }
}

// ---------------------------------------------------------------------------
// per-row: pre2 = h.Hw2, y = tanh(pre2+Hb2), s = 1-y^2,
//          w_j = s * Hw2_j * (1 - h_j^2)    (one wave per row)
// ---------------------------------------------------------------------------
__global__ __launch_bounds__(64) void hgrad_w(const bf16_t* __restrict__ h,
                                              const float* __restrict__ Hw2,
                                              const float* __restrict__ Hb2,
                                              bf16_t* __restrict__ w) {
  const int row = blockIdx.x;
  const int lane = threadIdx.x;
  float hv[10], wv[10];
  float pre2 = 0.f;
#pragma unroll
  for (int t = 0; t < 10; ++t) {
    const int j = lane + t * 64;
    hv[t] = (float)h[(size_t)row * 640 + j];
    wv[t] = Hw2[j];
    pre2 += hv[t] * wv[t];
  }
#pragma unroll
  for (int d = 1; d < 64; d <<= 1) pre2 += __shfl_xor(pre2, d, 64);
  const float y = fast_tanh(pre2 + Hb2[0]);
  const float s = 1.f - y * y;
#pragma unroll
  for (int t = 0; t < 10; ++t) {
    const int j = lane + t * 64;
    w[(size_t)row * 640 + j] = (bf16_t)(s * wv[t] * (1.f - hv[t] * hv[t]));
  }
}

// ---------------------------------------------------------------------------
extern "C" void kernel_launch(void* const* d_in, const int* in_sizes, int n_in,
                              void* d_out, int out_size, void* d_ws,
                              size_t ws_size, hipStream_t stream) {
  (void)in_sizes;
  (void)n_in;
  (void)out_size;
  (void)ws_size;
  // order: t, inp, Hw1, Hb1, Hw2, Hb2, Aw1, Ab1, Aw2, Ab2, Aw3, Ab3, u
  const float* inp = (const float*)d_in[1];
  const float* Hw1 = (const float*)d_in[2];
  const float* Hb1 = (const float*)d_in[3];
  const float* Hw2 = (const float*)d_in[4];
  const float* Hb2 = (const float*)d_in[5];
  const float* Aw1 = (const float*)d_in[6];
  const float* Ab1 = (const float*)d_in[7];
  const float* Aw2 = (const float*)d_in[8];
  const float* Ab2 = (const float*)d_in[9];
  const float* Aw3 = (const float*)d_in[10];
  const float* Ab3 = (const float*)d_in[11];
  const float* u = (const float*)d_in[12];
  float* out = (float*)d_out;

  // workspace layout (~38 MB)
  char* ws = (char*)d_ws;
  bf16_t* inp_bf = (bf16_t*)ws;   ws += (size_t)NROW * 256 * 2;
  bf16_t* Hw1_bf = (bf16_t*)ws;   ws += (size_t)256 * 640 * 2;
  bf16_t* Hw1T = (bf16_t*)ws;     ws += (size_t)640 * 256 * 2;
  bf16_t* Aw1T = (bf16_t*)ws;     ws += (size_t)512 * 128 * 2;
  bf16_t* Aw2T = (bf16_t*)ws;     ws += (size_t)1024 * 512 * 2;
  uint8_t* Aw3T8 = (uint8_t*)ws;  ws += (size_t)16384 * 1024;   // fp8 x64
  bf16_t* h_bf = (bf16_t*)ws;     ws += (size_t)NROW * 640 * 2;
  bf16_t* w_bf = (bf16_t*)ws;     ws += (size_t)NROW * 640 * 2;
  bf16_t* h1_bf = (bf16_t*)ws;    ws += (size_t)NROW * 512 * 2;
  uint8_t* h2_f8 = (uint8_t*)ws;  ws += (size_t)NROW * 1024;    // fp8 x64

  // ---- all conversions/transposes in one launch ----
  prep<<<16384 + 1184 + 736, 256, 0, stream>>>(inp, inp_bf, Hw1, Hw1_bf, Hw1T,
                                               Aw1, Aw1T, Aw2, Aw2T, Aw3,
                                               Aw3T8);

  // ---- H net ----
  gemm_bt<0><<<dim3(32, 5), 256, 0, stream>>>(inp_bf, 256, Hw1T, 256, 256, Hb1,
                                              h_bf, 640);
  hgrad_w<<<NROW, 64, 0, stream>>>(h_bf, Hw2, Hb2, w_bf);
  gemm_bt<1><<<dim3(32, 2), 256, 0, stream>>>(w_bf, 640, Hw1_bf, 640, 640,
                                              nullptr, out, 256);

  // ---- A net ----
  gemm_bt<0><<<dim3(32, 4), 256, 0, stream>>>(inp_bf, 256, Aw1T, 128, 128, Ab1,
                                              h1_bf, 512);
  gemm_bt<3><<<dim3(32, 8), 256, 0, stream>>>(h1_bf, 512, Aw2T, 512, 512, Ab2,
                                              h2_f8, 1024);
  gemm_a3_fp8<<<dim3(32, 128), 256, 0, stream>>>(h2_f8, Aw3T8, out, Ab3, u);
}

// Round 5
// 265.191 us; speedup vs baseline: 1.4075x; 1.0452x over previous
//
#include <hip/hip_runtime.h>
#include <hip/hip_bf16.h>
#include <cstdint>

// ---------------------------------------------------------------------------
// Hamilton_V5  R5: co-scheduled launches. A3 reverted to R3 shape (BK=64).
// Independent small GEMMs merged into big-grid launches so their exposed
// latency hides under large kernels. A3 writes dvA; final combine adds it.
// ---------------------------------------------------------------------------

typedef __bf16 bf16_t;
typedef __bf16 bf16x4_t __attribute__((ext_vector_type(4)));
typedef __bf16 bf16x8_t __attribute__((ext_vector_type(8)));
typedef float f32x4_t __attribute__((ext_vector_type(4)));
typedef float f32x16_t __attribute__((ext_vector_type(16)));
typedef int intx4_t __attribute__((ext_vector_type(4)));
typedef int intx8_t __attribute__((ext_vector_type(8)));

#define DIMD 128
#define NROW 4096
#define SMEM_BYTES 18432

// branchless tanh: t=2^(2x*log2e); tanh=1-2/(t+1).
__device__ __forceinline__ float fast_tanh(float x) {
  float t = __builtin_amdgcn_exp2f(x * 2.8853900817779268f);
  return 1.f - 2.f * __builtin_amdgcn_rcpf(t + 1.f);
}

// f32 -> fp8 e4m3 (OCP), RNE+sat via HW cvt
__device__ __forceinline__ uint8_t to_fp8(float x) {
  return (uint8_t)(__builtin_amdgcn_cvt_pk_fp8_f32(x, x, 0, false) & 0xff);
}

// async global->LDS, 16B per lane; LDS dest = wave-uniform base + lane*16
__device__ __forceinline__ void g2l16(const void* gp, void* lp) {
  __builtin_amdgcn_global_load_lds(
      reinterpret_cast<__attribute__((address_space(1))) void*>(
          reinterpret_cast<uintptr_t>(gp)),
      reinterpret_cast<__attribute__((address_space(3))) void*>(
          reinterpret_cast<uintptr_t>(lp)),
      16, 0, 0);
}

// ---------------------------------------------------------------------------
// bf16 GEMM body, C = A(MxK) * B^T(NxK)^T, 128x128x32 tile, 4 waves 2x2.
// LDS swizzle: row r's 16B k-chunk kc at slot kc ^ ((r>>1)&3)  (R2-verified 0
// conflicts). EPI 0: bf16 tanh(C+b); EPI 1: +/-C f32 to out; EPI 3: fp8 x64.
// ---------------------------------------------------------------------------
template <int EPI>
__device__ __forceinline__ void gemm_body(char* smem, int bx, int by,
                                          const bf16_t* A, int lda,
                                          const bf16_t* B, int ldb, int K,
                                          const float* bias, void* outp,
                                          int ldo) {
  constexpr int BK = 32;
  bf16_t* As = (bf16_t*)smem;       // 128*32
  bf16_t* Bs = As + 4096;

  const int m0 = bx * 128;
  const int n0 = by * 128;
  const int tid = threadIdx.x;
  const int wave = tid >> 6;
  const int lane = tid & 63;
  const int wm = wave >> 1;
  const int wn = wave & 1;

  const int sr = lane >> 2;
  const int sk = (((lane & 3) ^ ((sr >> 1) & 3)) * 8);
  const int fr = lane & 15;
  const int fk = (((lane >> 4) ^ ((fr >> 1) & 3)) * 8);

  f32x4_t acc[4][4] = {};

  for (int k0 = 0; k0 < K; k0 += BK) {
    if (k0) __syncthreads();
#pragma unroll
    for (int t = 0; t < 2; ++t) {
      const int rb = wave * 32 + t * 16;
      g2l16(A + (size_t)(m0 + rb + sr) * lda + (k0 + sk), As + rb * BK);
      g2l16(B + (size_t)(n0 + rb + sr) * ldb + (k0 + sk), Bs + rb * BK);
    }
    __syncthreads();

    bf16x8_t af[4], bb[4];
#pragma unroll
    for (int t = 0; t < 4; ++t) {
      af[t] = *(const bf16x8_t*)(As + (wm * 64 + t * 16 + fr) * BK + fk);
      bb[t] = *(const bf16x8_t*)(Bs + (wn * 64 + t * 16 + fr) * BK + fk);
    }
#pragma unroll
    for (int i = 0; i < 4; ++i)
#pragma unroll
      for (int j = 0; j < 4; ++j)
        acc[i][j] = __builtin_amdgcn_mfma_f32_16x16x32_bf16(af[i], bb[j],
                                                            acc[i][j], 0, 0, 0);
  }

  // C/D layout (m89): col = lane&15, row = (lane>>4)*4 + reg
  if constexpr (EPI == 0) {
    bf16_t* O = (bf16_t*)outp;
#pragma unroll
    for (int i = 0; i < 4; ++i) {
      const int row = m0 + wm * 64 + i * 16 + (lane >> 4) * 4;
#pragma unroll
      for (int j = 0; j < 4; ++j) {
        const int col = n0 + wn * 64 + j * 16 + fr;
        const float b = bias[col];
#pragma unroll
        for (int r = 0; r < 4; ++r)
          O[(size_t)(row + r) * ldo + col] = (bf16_t)fast_tanh(acc[i][j][r] + b);
      }
    }
  } else if constexpr (EPI == 1) {
    float* O = (float*)outp;
    const float sgn = (n0 >= DIMD) ? -1.f : 1.f;  // dv = -g[:, d:]
#pragma unroll
    for (int i = 0; i < 4; ++i) {
      const int row = m0 + wm * 64 + i * 16 + (lane >> 4) * 4;
#pragma unroll
      for (int j = 0; j < 4; ++j) {
        const int col = n0 + wn * 64 + j * 16 + fr;
#pragma unroll
        for (int r = 0; r < 4; ++r)
          O[(size_t)(row + r) * ldo + col] = sgn * acc[i][j][r];
      }
    }
  } else {  // EPI 3: fp8 x64 output
    uint8_t* O = (uint8_t*)outp;
#pragma unroll
    for (int i = 0; i < 4; ++i) {
      const int row = m0 + wm * 64 + i * 16 + (lane >> 4) * 4;
#pragma unroll
      for (int j = 0; j < 4; ++j) {
        const int col = n0 + wn * 64 + j * 16 + fr;
        const float b = bias[col];
#pragma unroll
        for (int r = 0; r < 4; ++r)
          O[(size_t)(row + r) * ldo + col] =
              to_fp8(64.f * fast_tanh(acc[i][j][r] + b));
      }
    }
  }
}

// ---------------------------------------------------------------------------
// A3 fused GEMM in MX-fp8 (R3 shape, BK=64): C = h2 @ Aw3T^T, then
// dvA[m, by] = sum_n tanh(C[m,n]+Ab3[n]) * u[n&127].  Scales 2^-6 both sides.
// ---------------------------------------------------------------------------
__device__ __forceinline__ void a3_body(char* smem, int bx, int by,
                                        const uint8_t* A, const uint8_t* B,
                                        float* dvA, const float* ab3,
                                        const float* uvec) {
  constexpr int BK = 64, K = 1024;
  uint8_t* As = (uint8_t*)smem;        // 8192
  uint8_t* Bs = As + 8192;             // 8192
  float* red = (float*)(smem + 16384); // 128
  float* us = red + 128;               // 128
  float* a3s = us + 128;               // 128

  const int m0 = bx * 128;
  const int n0 = by * 128;
  const int tid = threadIdx.x;
  const int wave = tid >> 6;
  const int lane = tid & 63;
  const int wm = wave >> 1;
  const int wn = wave & 1;

  if (tid < 128) {
    red[tid] = 0.f;
    us[tid] = uvec[tid];
    a3s[tid] = ab3[n0 + tid];
  }

  const int sr = lane >> 2;
  const int sk = ((lane & 3) ^ ((sr >> 1) & 3)) * 16;

  const int rl = lane & 31;
  const int w = (rl >> 1) & 3;
  const int c0 = lane >> 5;
  const int sLo = ((2 * c0) ^ w) * 16;
  const int sHi = ((2 * c0 + 1) ^ w) * 16;

  f32x16_t acc[2][2] = {};

  for (int k0 = 0; k0 < K; k0 += BK) {
    if (k0) __syncthreads();
#pragma unroll
    for (int t = 0; t < 2; ++t) {
      const int rb = t * 64 + wave * 16;
      g2l16(A + (size_t)(m0 + rb + sr) * K + (k0 + sk), As + rb * BK);
      g2l16(B + (size_t)(n0 + rb + sr) * K + (k0 + sk), Bs + rb * BK);
    }
    __syncthreads();

    intx8_t af[2], bf[2];
#pragma unroll
    for (int i = 0; i < 2; ++i) {
      const int ra = (wm * 64 + i * 32 + rl) * BK;
      intx4_t lo = *(const intx4_t*)(As + ra + sLo);
      intx4_t hi = *(const intx4_t*)(As + ra + sHi);
      af[i] = __builtin_shufflevector(lo, hi, 0, 1, 2, 3, 4, 5, 6, 7);
      const int rb2 = (wn * 64 + i * 32 + rl) * BK;
      intx4_t lob = *(const intx4_t*)(Bs + rb2 + sLo);
      intx4_t hib = *(const intx4_t*)(Bs + rb2 + sHi);
      bf[i] = __builtin_shufflevector(lob, hib, 0, 1, 2, 3, 4, 5, 6, 7);
    }
#pragma unroll
    for (int i = 0; i < 2; ++i)
#pragma unroll
      for (int j = 0; j < 2; ++j)
        acc[i][j] = __builtin_amdgcn_mfma_scale_f32_32x32x64_f8f6f4(
            af[i], bf[j], acc[i][j], 0, 0, 0, 0x79797979, 0, 0x79797979);
  }

  // C/D (m74/m101): col = lane&31, row = (reg&3) + 8*(reg>>2) + 4*(lane>>5)
  const int q = lane >> 5;
#pragma unroll
  for (int i = 0; i < 2; ++i) {
    float sums[16];
#pragma unroll
    for (int r = 0; r < 16; ++r) sums[r] = 0.f;
#pragma unroll
    for (int j = 0; j < 2; ++j) {
      const int c = wn * 64 + j * 32 + rl;
      const float uu = us[c];
      const float b3 = a3s[c];
#pragma unroll
      for (int r = 0; r < 16; ++r) sums[r] += fast_tanh(acc[i][j][r] + b3) * uu;
    }
#pragma unroll
    for (int d = 1; d < 32; d <<= 1)
#pragma unroll
      for (int r = 0; r < 16; ++r) sums[r] += __shfl_xor(sums[r], d, 64);
    if (rl == 0) {
      const int rowb = wm * 64 + i * 32 + 4 * q;
#pragma unroll
      for (int r = 0; r < 16; ++r)
        atomicAdd(&red[rowb + (r & 3) + 8 * (r >> 2)], sums[r]);
    }
  }
  __syncthreads();
  if (tid < 128) dvA[(size_t)(m0 + tid) * 128 + by] = red[tid];
}

// ---------------------------------------------------------------------------
// small helpers
// ---------------------------------------------------------------------------
__device__ __forceinline__ void tcvt_body(char* smem, const float* in,
                                          bf16_t* out, int R, int C, int bx,
                                          int by) {
  float(*t)[33] = (float(*)[33])smem;  // 32*33*4 = 4224 B
  const int c0 = bx * 32;
  const int r0 = by * 32;
  const int tx = threadIdx.x & 31;
  const int ty = threadIdx.x >> 5;
#pragma unroll
  for (int k = 0; k < 4; ++k)
    t[ty + k * 8][tx] = in[(size_t)(r0 + ty + k * 8) * C + c0 + tx];
  __syncthreads();
#pragma unroll
  for (int k = 0; k < 4; ++k)
    out[(size_t)(c0 + ty + k * 8) * R + r0 + tx] = (bf16_t)t[tx][ty + k * 8];
}

__device__ __forceinline__ void aw3t_body(char* smem, const float* Aw3,
                                          uint8_t* Aw3T8, int b) {
  float(*t)[33] = (float(*)[33])smem;
  const int c0 = (b & 511) * 32;
  const int r0 = (b >> 9) * 32;
  const int tx = threadIdx.x & 31;
  const int ty = threadIdx.x >> 5;
#pragma unroll
  for (int k = 0; k < 4; ++k)
    t[ty + k * 8][tx] = Aw3[(size_t)(r0 + ty + k * 8) * 16384 + c0 + tx];
  __syncthreads();
#pragma unroll
  for (int k = 0; k < 4; ++k)
    Aw3T8[(size_t)(c0 + ty + k * 8) * 1024 + r0 + tx] =
        to_fp8(64.f * t[tx][ty + k * 8]);
}

// one wave handles one row: pre2 = h.Hw2; w_j = s*Hw2_j*(1-h_j^2)
__device__ __forceinline__ void hgrad_row(int row, const bf16_t* h,
                                          const float* Hw2, const float* Hb2,
                                          bf16_t* wout) {
  const int lane = threadIdx.x & 63;
  float hv[10], wv[10];
  float pre2 = 0.f;
#pragma unroll
  for (int t = 0; t < 10; ++t) {
    const int j = lane + t * 64;
    hv[t] = (float)h[(size_t)row * 640 + j];
    wv[t] = Hw2[j];
    pre2 += hv[t] * wv[t];
  }
#pragma unroll
  for (int d = 1; d < 64; d <<= 1) pre2 += __shfl_xor(pre2, d, 64);
  const float y = fast_tanh(pre2 + Hb2[0]);
  const float s = 1.f - y * y;
#pragma unroll
  for (int t = 0; t < 10; ++t) {
    const int j = lane + t * 64;
    wout[(size_t)row * 640 + j] = (bf16_t)(s * wv[t] * (1.f - hv[t] * hv[t]));
  }
}

// ---------------------------------------------------------------------------
// L0: cvt inp+Hw1 (1184 blk) + small transposes (736 blk) = 1920 blocks
// ---------------------------------------------------------------------------
__global__ __launch_bounds__(256) void prep_small(
    const float* __restrict__ inp, bf16_t* __restrict__ inp_bf,
    const float* __restrict__ Hw1, bf16_t* __restrict__ Hw1_bf,
    bf16_t* __restrict__ Hw1T, const float* __restrict__ Aw1,
    bf16_t* __restrict__ Aw1T, const float* __restrict__ Aw2,
    bf16_t* __restrict__ Aw2T) {
  __shared__ __align__(16) char smem[4224];
  int b = blockIdx.x;
  if (b < 1184) {
    const int i = b * 256 + threadIdx.x;
    const int na4 = NROW * 256 / 4;
    const float4* in;
    bf16x4_t* out;
    int j;
    if (i < na4) {
      in = (const float4*)inp; out = (bf16x4_t*)inp_bf; j = i;
    } else {
      j = i - na4;
      if (j >= 256 * 640 / 4) return;
      in = (const float4*)Hw1; out = (bf16x4_t*)Hw1_bf;
    }
    const float4 v = in[j];
    bf16x4_t o = {(bf16_t)v.x, (bf16_t)v.y, (bf16_t)v.z, (bf16_t)v.w};
    out[j] = o;
  } else {
    int s = b - 1184;
    if (s < 160) tcvt_body(smem, Hw1, Hw1T, 256, 640, s % 20, s / 20);
    else if (s < 224) { s -= 160; tcvt_body(smem, Aw1, Aw1T, 128, 512, s % 16, s / 16); }
    else { s -= 224; tcvt_body(smem, Aw2, Aw2T, 512, 1024, s % 32, s / 32); }
  }
}

// ---------------------------------------------------------------------------
// L1: H-fwd gemm (160) + A1 gemm (128) + Aw3 fp8 transpose (16384)
// ---------------------------------------------------------------------------
__global__ __launch_bounds__(256) void launch1(
    const bf16_t* __restrict__ inp_bf, const bf16_t* __restrict__ Hw1T,
    const float* __restrict__ Hb1, bf16_t* __restrict__ h_bf,
    const bf16_t* __restrict__ Aw1T, const float* __restrict__ Ab1,
    bf16_t* __restrict__ h1_bf, const float* __restrict__ Aw3,
    uint8_t* __restrict__ Aw3T8) {
  __shared__ __align__(16) char smem[SMEM_BYTES];
  const int b = blockIdx.x;
  if (b < 160) {
    gemm_body<0>(smem, b % 32, b / 32, inp_bf, 256, Hw1T, 256, 256, Hb1, h_bf, 640);
  } else if (b < 288) {
    const int i = b - 160;
    gemm_body<0>(smem, i % 32, i / 32, inp_bf, 256, Aw1T, 128, 128, Ab1, h1_bf, 512);
  } else {
    aw3t_body(smem, Aw3, Aw3T8, b - 288);
  }
}

// ---------------------------------------------------------------------------
// L2: A2 gemm->fp8 (256) + hgrad_w (1024 blocks x 4 rows)
// ---------------------------------------------------------------------------
__global__ __launch_bounds__(256) void launch2(
    const bf16_t* __restrict__ h1_bf, const bf16_t* __restrict__ Aw2T,
    const float* __restrict__ Ab2, uint8_t* __restrict__ h2_f8,
    const bf16_t* __restrict__ h_bf, const float* __restrict__ Hw2,
    const float* __restrict__ Hb2, bf16_t* __restrict__ w_bf) {
  __shared__ __align__(16) char smem[SMEM_BYTES];
  const int b = blockIdx.x;
  if (b < 256) {
    gemm_body<3>(smem, b % 32, b / 32, h1_bf, 512, Aw2T, 512, 512, Ab2, h2_f8, 1024);
  } else {
    const int row = (b - 256) * 4 + (threadIdx.x >> 6);
    hgrad_row(row, h_bf, Hw2, Hb2, w_bf);
  }
}

// ---------------------------------------------------------------------------
// L3: H-bwd gemm (64) + A3 fused fp8 (4096)
// ---------------------------------------------------------------------------
__global__ __launch_bounds__(256) void launch3(
    const bf16_t* __restrict__ w_bf, const bf16_t* __restrict__ Hw1_bf,
    float* __restrict__ out, const uint8_t* __restrict__ h2_f8,
    const uint8_t* __restrict__ Aw3T8, float* __restrict__ dvA,
    const float* __restrict__ Ab3, const float* __restrict__ uvec) {
  __shared__ __align__(16) char smem[SMEM_BYTES];
  const int b = blockIdx.x;
  if (b < 64) {
    gemm_body<1>(smem, b % 32, b / 32, w_bf, 640, Hw1_bf, 640, 640, nullptr, out, 256);
  } else {
    const int i = b - 64;
    a3_body(smem, i & 31, i >> 5, h2_f8, Aw3T8, dvA, Ab3, uvec);
  }
}

// ---------------------------------------------------------------------------
// L4: out[m, 128+j] += dvA[m*128+j]   (2048 blocks)
// ---------------------------------------------------------------------------
__global__ __launch_bounds__(256) void combine(float* __restrict__ out,
                                               const float* __restrict__ dvA) {
  const int i = blockIdx.x * 256 + threadIdx.x;
  out[(size_t)(i >> 7) * 256 + 128 + (i & 127)] += dvA[i];
}

// ---------------------------------------------------------------------------
extern "C" void kernel_launch(void* const* d_in, const int* in_sizes, int n_in,
                              void* d_out, int out_size, void* d_ws,
                              size_t ws_size, hipStream_t stream) {
  (void)in_sizes; (void)n_in; (void)out_size; (void)ws_size;
  const float* inp = (const float*)d_in[1];
  const float* Hw1 = (const float*)d_in[2];
  const float* Hb1 = (const float*)d_in[3];
  const float* Hw2 = (const float*)d_in[4];
  const float* Hb2 = (const float*)d_in[5];
  const float* Aw1 = (const float*)d_in[6];
  const float* Ab1 = (const float*)d_in[7];
  const float* Aw2 = (const float*)d_in[8];
  const float* Ab2 = (const float*)d_in[9];
  const float* Aw3 = (const float*)d_in[10];
  const float* Ab3 = (const float*)d_in[11];
  const float* u = (const float*)d_in[12];
  float* out = (float*)d_out;

  char* ws = (char*)d_ws;
  bf16_t* inp_bf = (bf16_t*)ws;   ws += (size_t)NROW * 256 * 2;
  bf16_t* Hw1_bf = (bf16_t*)ws;   ws += (size_t)256 * 640 * 2;
  bf16_t* Hw1T = (bf16_t*)ws;     ws += (size_t)640 * 256 * 2;
  bf16_t* Aw1T = (bf16_t*)ws;     ws += (size_t)512 * 128 * 2;
  bf16_t* Aw2T = (bf16_t*)ws;     ws += (size_t)1024 * 512 * 2;
  uint8_t* Aw3T8 = (uint8_t*)ws;  ws += (size_t)16384 * 1024;
  bf16_t* h_bf = (bf16_t*)ws;     ws += (size_t)NROW * 640 * 2;
  bf16_t* w_bf = (bf16_t*)ws;     ws += (size_t)NROW * 640 * 2;
  bf16_t* h1_bf = (bf16_t*)ws;    ws += (size_t)NROW * 512 * 2;
  uint8_t* h2_f8 = (uint8_t*)ws;  ws += (size_t)NROW * 1024;
  float* dvA = (float*)ws;        ws += (size_t)NROW * 128 * 4;

  prep_small<<<1920, 256, 0, stream>>>(inp, inp_bf, Hw1, Hw1_bf, Hw1T, Aw1,
                                       Aw1T, Aw2, Aw2T);
  launch1<<<288 + 16384, 256, 0, stream>>>(inp_bf, Hw1T, Hb1, h_bf, Aw1T, Ab1,
                                           h1_bf, Aw3, Aw3T8);
  launch2<<<256 + 1024, 256, 0, stream>>>(h1_bf, Aw2T, Ab2, h2_f8, h_bf, Hw2,
                                          Hb2, w_bf);
  launch3<<<64 + 4096, 256, 0, stream>>>(w_bf, Hw1_bf, out, h2_f8, Aw3T8, dvA,
                                         Ab3, u);
  combine<<<2048, 256, 0, stream>>>(out, dvA);
}

// Round 6
// 252.862 us; speedup vs baseline: 1.4761x; 1.0488x over previous
//
#include <hip/hip_runtime.h>
#include <hip/hip_bf16.h>
#include <cstdint>

// ---------------------------------------------------------------------------
// Hamilton_V5  R6:
//  - A3: wave-grid (4,1), BM=256, wave-tile 64x128 -> LDS read/DMA traffic
//    x0.75 per unit work (A3 is LDS-pipe bound: 2.1M ds_read_b128 = 41us/CU
//    vs 29us MFMA floor).
//  - Aw3 fp8 transpose split across L1/L2 so A2+hgrad hide under it.
//  - out zeroed in L2; H-bwd dv-half and A3 use atomicAdd -> combine launch
//    gone (two-addend fp32 sums commute -> bitwise identical).
//  - Transpose emits uchar4 stores instead of byte stores.
// ---------------------------------------------------------------------------

typedef __bf16 bf16_t;
typedef __bf16 bf16x4_t __attribute__((ext_vector_type(4)));
typedef __bf16 bf16x8_t __attribute__((ext_vector_type(8)));
typedef float f32x4_t __attribute__((ext_vector_type(4)));
typedef float f32x16_t __attribute__((ext_vector_type(16)));
typedef int intx4_t __attribute__((ext_vector_type(4)));
typedef int intx8_t __attribute__((ext_vector_type(8)));

#define DIMD 128
#define NROW 4096
#define SMEM_BYTES 18432   // launch1/launch2 (gemm 16.4K, transpose 4.2K)
#define SMEM3_BYTES 26624  // launch3 (a3: 24576 + 512*4)

// branchless tanh: t=2^(2x*log2e); tanh=1-2/(t+1).
__device__ __forceinline__ float fast_tanh(float x) {
  float t = __builtin_amdgcn_exp2f(x * 2.8853900817779268f);
  return 1.f - 2.f * __builtin_amdgcn_rcpf(t + 1.f);
}

// f32 -> fp8 e4m3 (OCP), RNE+sat via HW cvt
__device__ __forceinline__ uint8_t to_fp8(float x) {
  return (uint8_t)(__builtin_amdgcn_cvt_pk_fp8_f32(x, x, 0, false) & 0xff);
}

// async global->LDS, 16B per lane; LDS dest = wave-uniform base + lane*16
__device__ __forceinline__ void g2l16(const void* gp, void* lp) {
  __builtin_amdgcn_global_load_lds(
      reinterpret_cast<__attribute__((address_space(1))) void*>(
          reinterpret_cast<uintptr_t>(gp)),
      reinterpret_cast<__attribute__((address_space(3))) void*>(
          reinterpret_cast<uintptr_t>(lp)),
      16, 0, 0);
}

// ---------------------------------------------------------------------------
// bf16 GEMM body, C = A(MxK) * B^T(NxK)^T, 128x128x32 tile, 4 waves 2x2.
// LDS swizzle: row r's 16B k-chunk kc at slot kc ^ ((r>>1)&3) (0 conflicts).
// EPI 0: bf16 tanh(C+b); EPI 1: dx plain store / dv atomicAdd(-C);
// EPI 3: fp8 x64.
// ---------------------------------------------------------------------------
template <int EPI>
__device__ __forceinline__ void gemm_body(char* smem, int bx, int by,
                                          const bf16_t* A, int lda,
                                          const bf16_t* B, int ldb, int K,
                                          const float* bias, void* outp,
                                          int ldo) {
  constexpr int BK = 32;
  bf16_t* As = (bf16_t*)smem;  // 128*32
  bf16_t* Bs = As + 4096;

  const int m0 = bx * 128;
  const int n0 = by * 128;
  const int tid = threadIdx.x;
  const int wave = tid >> 6;
  const int lane = tid & 63;
  const int wm = wave >> 1;
  const int wn = wave & 1;

  const int sr = lane >> 2;
  const int sk = (((lane & 3) ^ ((sr >> 1) & 3)) * 8);
  const int fr = lane & 15;
  const int fk = (((lane >> 4) ^ ((fr >> 1) & 3)) * 8);

  f32x4_t acc[4][4] = {};

  for (int k0 = 0; k0 < K; k0 += BK) {
    if (k0) __syncthreads();
#pragma unroll
    for (int t = 0; t < 2; ++t) {
      const int rb = wave * 32 + t * 16;
      g2l16(A + (size_t)(m0 + rb + sr) * lda + (k0 + sk), As + rb * BK);
      g2l16(B + (size_t)(n0 + rb + sr) * ldb + (k0 + sk), Bs + rb * BK);
    }
    __syncthreads();

    bf16x8_t af[4], bb[4];
#pragma unroll
    for (int t = 0; t < 4; ++t) {
      af[t] = *(const bf16x8_t*)(As + (wm * 64 + t * 16 + fr) * BK + fk);
      bb[t] = *(const bf16x8_t*)(Bs + (wn * 64 + t * 16 + fr) * BK + fk);
    }
#pragma unroll
    for (int i = 0; i < 4; ++i)
#pragma unroll
      for (int j = 0; j < 4; ++j)
        acc[i][j] = __builtin_amdgcn_mfma_f32_16x16x32_bf16(af[i], bb[j],
                                                            acc[i][j], 0, 0, 0);
  }

  // C/D layout (m89): col = lane&15, row = (lane>>4)*4 + reg
  if constexpr (EPI == 0) {
    bf16_t* O = (bf16_t*)outp;
#pragma unroll
    for (int i = 0; i < 4; ++i) {
      const int row = m0 + wm * 64 + i * 16 + (lane >> 4) * 4;
#pragma unroll
      for (int j = 0; j < 4; ++j) {
        const int col = n0 + wn * 64 + j * 16 + fr;
        const float b = bias[col];
#pragma unroll
        for (int r = 0; r < 4; ++r)
          O[(size_t)(row + r) * ldo + col] = (bf16_t)fast_tanh(acc[i][j][r] + b);
      }
    }
  } else if constexpr (EPI == 1) {
    float* O = (float*)outp;
    const bool dx = (n0 < DIMD);
#pragma unroll
    for (int i = 0; i < 4; ++i) {
      const int row = m0 + wm * 64 + i * 16 + (lane >> 4) * 4;
#pragma unroll
      for (int j = 0; j < 4; ++j) {
        const int col = n0 + wn * 64 + j * 16 + fr;
#pragma unroll
        for (int r = 0; r < 4; ++r) {
          const size_t idx = (size_t)(row + r) * ldo + col;
          if (dx) O[idx] = acc[i][j][r];
          else atomicAdd(&O[idx], -acc[i][j][r]);  // dv_H shares with dvA
        }
      }
    }
  } else {  // EPI 3: fp8 x64 output
    uint8_t* O = (uint8_t*)outp;
#pragma unroll
    for (int i = 0; i < 4; ++i) {
      const int row = m0 + wm * 64 + i * 16 + (lane >> 4) * 4;
#pragma unroll
      for (int j = 0; j < 4; ++j) {
        const int col = n0 + wn * 64 + j * 16 + fr;
        const float b = bias[col];
#pragma unroll
        for (int r = 0; r < 4; ++r)
          O[(size_t)(row + r) * ldo + col] =
              to_fp8(64.f * fast_tanh(acc[i][j][r] + b));
      }
    }
  }
}

// ---------------------------------------------------------------------------
// A3 fused GEMM, MX-fp8, wave grid (4,1): BM=256, BN=128, BK=64. Each wave
// computes 64x128 (2x4 mfma 32x32x64) -> LDS reads/DMA per unit work x0.75.
// out[m, 128+by] += sum_n tanh(C[m,n]+Ab3[n]) * u[n] via global atomicAdd.
// ---------------------------------------------------------------------------
__device__ __forceinline__ void a3_body(char* smem, int bx, int by,
                                        const uint8_t* A, const uint8_t* B,
                                        float* out, const float* ab3,
                                        const float* uvec) {
  constexpr int BK = 64, K = 1024;
  uint8_t* As = (uint8_t*)smem;         // 256*64 = 16384
  uint8_t* Bs = As + 16384;             // 128*64 = 8192
  float* red = (float*)(smem + 24576);  // 256
  float* us = red + 256;                // 128
  float* a3s = us + 128;                // 128

  const int m0 = bx * 256;
  const int n0 = by * 128;
  const int tid = threadIdx.x;
  const int wave = tid >> 6;
  const int lane = tid & 63;

  red[tid] = 0.f;
  if (tid < 128) {
    us[tid] = uvec[tid];
    a3s[tid] = ab3[n0 + tid];
  }

  const int sr = lane >> 2;
  const int sk = ((lane & 3) ^ ((sr >> 1) & 3)) * 16;

  const int rl = lane & 31;
  const int w = (rl >> 1) & 3;
  const int c0 = lane >> 5;
  const int sLo = ((2 * c0) ^ w) * 16;
  const int sHi = ((2 * c0 + 1) ^ w) * 16;

  f32x16_t acc[2][4] = {};

  for (int k0 = 0; k0 < K; k0 += BK) {
    if (k0) __syncthreads();
#pragma unroll
    for (int t = 0; t < 4; ++t) {
      const int rb = t * 64 + wave * 16;
      g2l16(A + (size_t)(m0 + rb + sr) * K + (k0 + sk), As + rb * BK);
    }
#pragma unroll
    for (int t = 0; t < 2; ++t) {
      const int rb = t * 64 + wave * 16;
      g2l16(B + (size_t)(n0 + rb + sr) * K + (k0 + sk), Bs + rb * BK);
    }
    __syncthreads();

    intx8_t af[2], bfr[4];
#pragma unroll
    for (int i = 0; i < 2; ++i) {
      const int ra = (wave * 64 + i * 32 + rl) * BK;
      intx4_t lo = *(const intx4_t*)(As + ra + sLo);
      intx4_t hi = *(const intx4_t*)(As + ra + sHi);
      af[i] = __builtin_shufflevector(lo, hi, 0, 1, 2, 3, 4, 5, 6, 7);
    }
#pragma unroll
    for (int j = 0; j < 4; ++j) {
      const int rb2 = (j * 32 + rl) * BK;
      intx4_t lob = *(const intx4_t*)(Bs + rb2 + sLo);
      intx4_t hib = *(const intx4_t*)(Bs + rb2 + sHi);
      bfr[j] = __builtin_shufflevector(lob, hib, 0, 1, 2, 3, 4, 5, 6, 7);
    }
#pragma unroll
    for (int i = 0; i < 2; ++i)
#pragma unroll
      for (int j = 0; j < 4; ++j)
        acc[i][j] = __builtin_amdgcn_mfma_scale_f32_32x32x64_f8f6f4(
            af[i], bfr[j], acc[i][j], 0, 0, 0, 0x79797979, 0, 0x79797979);
  }

  // C/D (m74/m101): col = lane&31, row = (reg&3) + 8*(reg>>2) + 4*(lane>>5)
  const int q = lane >> 5;
#pragma unroll
  for (int i = 0; i < 2; ++i) {
    float sums[16];
#pragma unroll
    for (int r = 0; r < 16; ++r) sums[r] = 0.f;
#pragma unroll
    for (int j = 0; j < 4; ++j) {
      const int c = j * 32 + rl;
      const float uu = us[c];
      const float b3 = a3s[c];
#pragma unroll
      for (int r = 0; r < 16; ++r) sums[r] += fast_tanh(acc[i][j][r] + b3) * uu;
    }
#pragma unroll
    for (int d = 1; d < 32; d <<= 1)
#pragma unroll
      for (int r = 0; r < 16; ++r) sums[r] += __shfl_xor(sums[r], d, 64);
    if (rl == 0) {
      const int rowb = wave * 64 + i * 32 + 4 * q;
#pragma unroll
      for (int r = 0; r < 16; ++r)
        atomicAdd(&red[rowb + (r & 3) + 8 * (r >> 2)], sums[r]);
    }
  }
  __syncthreads();
  atomicAdd(&out[(size_t)(m0 + tid) * 256 + 128 + by], red[tid]);
}

// ---------------------------------------------------------------------------
// transposes
// ---------------------------------------------------------------------------
__device__ __forceinline__ void tcvt_body(char* smem, const float* in,
                                          bf16_t* out, int R, int C, int bx,
                                          int by) {
  float(*t)[33] = (float(*)[33])smem;  // 4224 B
  const int c0 = bx * 32;
  const int r0 = by * 32;
  const int tx = threadIdx.x & 31;
  const int ty = threadIdx.x >> 5;
#pragma unroll
  for (int k = 0; k < 4; ++k)
    t[ty + k * 8][tx] = in[(size_t)(r0 + ty + k * 8) * C + c0 + tx];
  __syncthreads();
#pragma unroll
  for (int k = 0; k < 4; ++k)
    out[(size_t)(c0 + ty + k * 8) * R + r0 + tx] = (bf16_t)t[tx][ty + k * 8];
}

// Aw3 (1024 x 16384) tile -> fp8 x64, transposed (16384 x 1024), uchar4 store
__device__ __forceinline__ void aw3t_body(char* smem, const float* Aw3,
                                          uint8_t* Aw3T8, int b) {
  float(*t)[33] = (float(*)[33])smem;  // t[r_local][c_local]
  const int c0 = (b & 511) * 32;
  const int r0 = (b >> 9) * 32;
  const int tx = threadIdx.x & 31;
  const int ty = threadIdx.x >> 5;
#pragma unroll
  for (int k = 0; k < 4; ++k)
    t[ty + k * 8][tx] = Aw3[(size_t)(r0 + ty + k * 8) * 16384 + c0 + tx];
  __syncthreads();
  const int cl = threadIdx.x >> 3;        // 0..31 output row (Aw3 col)
  const int j = (threadIdx.x & 7) * 4;    // 4-byte chunk of input rows
  uchar4 v;
  v.x = to_fp8(64.f * t[j + 0][cl]);
  v.y = to_fp8(64.f * t[j + 1][cl]);
  v.z = to_fp8(64.f * t[j + 2][cl]);
  v.w = to_fp8(64.f * t[j + 3][cl]);
  *(uchar4*)(Aw3T8 + (size_t)(c0 + cl) * 1024 + r0 + j) = v;
}

// one wave handles one row: pre2 = h.Hw2; w_j = s*Hw2_j*(1-h_j^2)
__device__ __forceinline__ void hgrad_row(int row, const bf16_t* h,
                                          const float* Hw2, const float* Hb2,
                                          bf16_t* wout) {
  const int lane = threadIdx.x & 63;
  float hv[10], wv[10];
  float pre2 = 0.f;
#pragma unroll
  for (int t = 0; t < 10; ++t) {
    const int j = lane + t * 64;
    hv[t] = (float)h[(size_t)row * 640 + j];
    wv[t] = Hw2[j];
    pre2 += hv[t] * wv[t];
  }
#pragma unroll
  for (int d = 1; d < 64; d <<= 1) pre2 += __shfl_xor(pre2, d, 64);
  const float y = fast_tanh(pre2 + Hb2[0]);
  const float s = 1.f - y * y;
#pragma unroll
  for (int t = 0; t < 10; ++t) {
    const int j = lane + t * 64;
    wout[(size_t)row * 640 + j] = (bf16_t)(s * wv[t] * (1.f - hv[t] * hv[t]));
  }
}

// ---------------------------------------------------------------------------
// L0: inp cvt (1024) + Hw1T (160) + Aw1T (64) = 1248 blocks
// ---------------------------------------------------------------------------
__global__ __launch_bounds__(256) void launch0(
    const float* __restrict__ inp, bf16_t* __restrict__ inp_bf,
    const float* __restrict__ Hw1, bf16_t* __restrict__ Hw1T,
    const float* __restrict__ Aw1, bf16_t* __restrict__ Aw1T) {
  __shared__ __align__(16) char smem[4224];
  int b = blockIdx.x;
  if (b < 1024) {
    const int i = b * 256 + threadIdx.x;
    const float4 v = ((const float4*)inp)[i];
    bf16x4_t o = {(bf16_t)v.x, (bf16_t)v.y, (bf16_t)v.z, (bf16_t)v.w};
    ((bf16x4_t*)inp_bf)[i] = o;
  } else if (b < 1184) {
    int s = b - 1024;
    tcvt_body(smem, Hw1, Hw1T, 256, 640, s % 20, s / 20);
  } else {
    int s = b - 1184;
    tcvt_body(smem, Aw1, Aw1T, 128, 512, s % 16, s / 16);
  }
}

// ---------------------------------------------------------------------------
// L1: Hfwd (160) + A1 (128) + Aw2T (512) + Hw1_bf cvt (160) + Aw3T[0:8192]
//     = 9152 blocks
// ---------------------------------------------------------------------------
__global__ __launch_bounds__(256) void launch1(
    const bf16_t* __restrict__ inp_bf, const bf16_t* __restrict__ Hw1T,
    const float* __restrict__ Hb1, bf16_t* __restrict__ h_bf,
    const bf16_t* __restrict__ Aw1T, const float* __restrict__ Ab1,
    bf16_t* __restrict__ h1_bf, const float* __restrict__ Aw2,
    bf16_t* __restrict__ Aw2T, const float* __restrict__ Hw1,
    bf16_t* __restrict__ Hw1_bf, const float* __restrict__ Aw3,
    uint8_t* __restrict__ Aw3T8) {
  __shared__ __align__(16) char smem[SMEM_BYTES];
  const int b = blockIdx.x;
  if (b < 160) {
    gemm_body<0>(smem, b % 32, b / 32, inp_bf, 256, Hw1T, 256, 256, Hb1, h_bf, 640);
  } else if (b < 288) {
    const int i = b - 160;
    gemm_body<0>(smem, i % 32, i / 32, inp_bf, 256, Aw1T, 128, 128, Ab1, h1_bf, 512);
  } else if (b < 800) {
    const int s = b - 288;
    tcvt_body(smem, Aw2, Aw2T, 512, 1024, s % 32, s / 32);
  } else if (b < 960) {
    const int i = (b - 800) * 256 + threadIdx.x;
    const float4 v = ((const float4*)Hw1)[i];
    bf16x4_t o = {(bf16_t)v.x, (bf16_t)v.y, (bf16_t)v.z, (bf16_t)v.w};
    ((bf16x4_t*)Hw1_bf)[i] = o;
  } else {
    aw3t_body(smem, Aw3, Aw3T8, b - 960);
  }
}

// ---------------------------------------------------------------------------
// L2: A2->fp8 (256) + hgrad (1024) + zero-out (1024) + Aw3T[8192:16384]
//     = 10496 blocks
// ---------------------------------------------------------------------------
__global__ __launch_bounds__(256) void launch2(
    const bf16_t* __restrict__ h1_bf, const bf16_t* __restrict__ Aw2T,
    const float* __restrict__ Ab2, uint8_t* __restrict__ h2_f8,
    const bf16_t* __restrict__ h_bf, const float* __restrict__ Hw2,
    const float* __restrict__ Hb2, bf16_t* __restrict__ w_bf,
    float* __restrict__ out, const float* __restrict__ Aw3,
    uint8_t* __restrict__ Aw3T8) {
  __shared__ __align__(16) char smem[SMEM_BYTES];
  const int b = blockIdx.x;
  if (b < 256) {
    gemm_body<3>(smem, b % 32, b / 32, h1_bf, 512, Aw2T, 512, 512, Ab2, h2_f8, 1024);
  } else if (b < 1280) {
    const int row = (b - 256) * 4 + (threadIdx.x >> 6);
    hgrad_row(row, h_bf, Hw2, Hb2, w_bf);
  } else if (b < 2304) {
    const int i = (b - 1280) * 256 + threadIdx.x;
    ((float4*)out)[i] = make_float4(0.f, 0.f, 0.f, 0.f);
  } else {
    aw3t_body(smem, Aw3, Aw3T8, 8192 + (b - 2304));
  }
}

// ---------------------------------------------------------------------------
// L3: Hbwd (64) + A3 fused fp8 (2048, BM=256) = 2112 blocks
// ---------------------------------------------------------------------------
__global__ __launch_bounds__(256) void launch3(
    const bf16_t* __restrict__ w_bf, const bf16_t* __restrict__ Hw1_bf,
    float* __restrict__ out, const uint8_t* __restrict__ h2_f8,
    const uint8_t* __restrict__ Aw3T8, const float* __restrict__ Ab3,
    const float* __restrict__ uvec) {
  __shared__ __align__(16) char smem[SMEM3_BYTES];
  const int b = blockIdx.x;
  if (b < 64) {
    gemm_body<1>(smem, b % 32, b / 32, w_bf, 640, Hw1_bf, 640, 640, nullptr, out, 256);
  } else {
    const int i = b - 64;
    a3_body(smem, i & 15, i >> 4, h2_f8, Aw3T8, out, Ab3, uvec);
  }
}

// ---------------------------------------------------------------------------
extern "C" void kernel_launch(void* const* d_in, const int* in_sizes, int n_in,
                              void* d_out, int out_size, void* d_ws,
                              size_t ws_size, hipStream_t stream) {
  (void)in_sizes; (void)n_in; (void)out_size; (void)ws_size;
  const float* inp = (const float*)d_in[1];
  const float* Hw1 = (const float*)d_in[2];
  const float* Hb1 = (const float*)d_in[3];
  const float* Hw2 = (const float*)d_in[4];
  const float* Hb2 = (const float*)d_in[5];
  const float* Aw1 = (const float*)d_in[6];
  const float* Ab1 = (const float*)d_in[7];
  const float* Aw2 = (const float*)d_in[8];
  const float* Ab2 = (const float*)d_in[9];
  const float* Aw3 = (const float*)d_in[10];
  const float* Ab3 = (const float*)d_in[11];
  const float* u = (const float*)d_in[12];
  float* out = (float*)d_out;

  char* ws = (char*)d_ws;
  bf16_t* inp_bf = (bf16_t*)ws;   ws += (size_t)NROW * 256 * 2;
  bf16_t* Hw1_bf = (bf16_t*)ws;   ws += (size_t)256 * 640 * 2;
  bf16_t* Hw1T = (bf16_t*)ws;     ws += (size_t)640 * 256 * 2;
  bf16_t* Aw1T = (bf16_t*)ws;     ws += (size_t)512 * 128 * 2;
  bf16_t* Aw2T = (bf16_t*)ws;     ws += (size_t)1024 * 512 * 2;
  uint8_t* Aw3T8 = (uint8_t*)ws;  ws += (size_t)16384 * 1024;
  bf16_t* h_bf = (bf16_t*)ws;     ws += (size_t)NROW * 640 * 2;
  bf16_t* w_bf = (bf16_t*)ws;     ws += (size_t)NROW * 640 * 2;
  bf16_t* h1_bf = (bf16_t*)ws;    ws += (size_t)NROW * 512 * 2;
  uint8_t* h2_f8 = (uint8_t*)ws;  ws += (size_t)NROW * 1024;

  launch0<<<1248, 256, 0, stream>>>(inp, inp_bf, Hw1, Hw1T, Aw1, Aw1T);
  launch1<<<9152, 256, 0, stream>>>(inp_bf, Hw1T, Hb1, h_bf, Aw1T, Ab1, h1_bf,
                                    Aw2, Aw2T, Hw1, Hw1_bf, Aw3, Aw3T8);
  launch2<<<10496, 256, 0, stream>>>(h1_bf, Aw2T, Ab2, h2_f8, h_bf, Hw2, Hb2,
                                     w_bf, out, Aw3, Aw3T8);
  launch3<<<2112, 256, 0, stream>>>(w_bf, Hw1_bf, out, h2_f8, Aw3T8, Ab3, u);
}